// Round 6
// baseline (529.926 us; speedup 1.0000x reference)
//
#include <hip/hip_runtime.h>
#include <hip/hip_fp16.h>

#define NNODES 50000
#define NEDGES 800000
#define EP (NEDGES + NNODES)   // 850000 edges incl. self-loops
#define CAP 64                 // per-node LDS edge cache in aggregate
#define NB 196                 // dst buckets of 256 nodes: ceil(50000/256)
#define CHUNK 8192             // edges per partition block

// ---------------- CSR build: two-level counting sort ----------------
__global__ __launch_bounds__(256) void bucket_hist_kernel(const int* __restrict__ ei, int* __restrict__ bucketHist){
  __shared__ int lh[NB];
  int t = threadIdx.x;
  for(int i = t; i < NB; i += 256) lh[i] = 0;
  __syncthreads();
  int base = blockIdx.x*CHUNK;
  #pragma unroll
  for(int k = 0; k < CHUNK; k += 256){
    int e = base + k + t;
    if(e < EP){
      int d = (e < NEDGES) ? ei[NEDGES + e] : (e - NEDGES);
      atomicAdd(&lh[d >> 8], 1);
    }
  }
  __syncthreads();
  for(int i = t; i < NB; i += 256) if(lh[i]) atomicAdd(&bucketHist[i], lh[i]);
}

__global__ __launch_bounds__(256) void bucket_scan_kernel(const int* __restrict__ bucketHist,
                                                          int* __restrict__ bucketBase,
                                                          int* __restrict__ bucketCursor,
                                                          int* __restrict__ rowptr){
  __shared__ int sb[256];
  int t = threadIdx.x;
  int v = (t < NB) ? bucketHist[t] : 0;
  sb[t] = v; __syncthreads();
  int acc = v;
  #pragma unroll
  for(int d = 1; d < 256; d <<= 1){
    int o = (t >= d) ? sb[t-d] : 0;
    __syncthreads();
    acc += o; sb[t] = acc;
    __syncthreads();
  }
  int excl = acc - v;
  if(t <= NB) bucketBase[t] = excl;
  if(t <  NB) bucketCursor[t] = excl;
  if(t == 0)  rowptr[NNODES] = EP;
}

__global__ __launch_bounds__(256) void partition_kernel(const int* __restrict__ ei,
                                                        int* __restrict__ bucketCursor,
                                                        unsigned int* __restrict__ edgebuf){
  __shared__ unsigned int stage[CHUNK];      // 32 KB
  __shared__ int lh[NB], lbase[NB], lcur[NB], gbase[NB];
  __shared__ int sb[256];
  int t = threadIdx.x;
  for(int i = t; i < NB; i += 256) lh[i] = 0;
  __syncthreads();
  int base = blockIdx.x*CHUNK;
  unsigned int pk[CHUNK/256];
  #pragma unroll
  for(int k = 0; k < CHUNK/256; k++){
    int e = base + k*256 + t;
    unsigned int p = 0xffffffffu;
    if(e < EP){
      int s, d;
      if(e < NEDGES){ s = ei[e]; d = ei[NEDGES + e]; }
      else          { s = d = e - NEDGES; }
      p = ((unsigned int)d << 16) | (unsigned int)s;
      atomicAdd(&lh[d >> 8], 1);
    }
    pk[k] = p;
  }
  __syncthreads();
  int v = (t < NB) ? lh[t] : 0;
  sb[t] = v; __syncthreads();
  int acc = v;
  #pragma unroll
  for(int d = 1; d < 256; d <<= 1){
    int o = (t >= d) ? sb[t-d] : 0;
    __syncthreads();
    acc += o; sb[t] = acc;
    __syncthreads();
  }
  int excl = acc - v;
  if(t < NB){
    lbase[t] = excl; lcur[t] = excl;
    gbase[t] = v ? atomicAdd(&bucketCursor[t], v) : 0;
  }
  __syncthreads();
  #pragma unroll
  for(int k = 0; k < CHUNK/256; k++){
    unsigned int p = pk[k];
    if(p != 0xffffffffu){
      int bin = p >> 24;
      int r = atomicAdd(&lcur[bin], 1);
      stage[r] = p;
    }
  }
  __syncthreads();
  int nvalid = EP - base; if(nvalid > CHUNK) nvalid = CHUNK;
  for(int j = t; j < nvalid; j += 256){
    unsigned int p = stage[j];
    int bin = p >> 24;
    edgebuf[gbase[bin] + (j - lbase[bin])] = p;
  }
}

__global__ __launch_bounds__(256) void bucket_sort_kernel(const unsigned int* __restrict__ edgebuf,
                                                          const int* __restrict__ bucketBase,
                                                          int* __restrict__ rowptr,
                                                          int* __restrict__ esrc){
  __shared__ int lh[256], lcur[256], sb[256];
  int b = blockIdx.x, t = threadIdx.x;
  int lo = bucketBase[b], hi = bucketBase[b+1];
  lh[t] = 0;
  __syncthreads();
  for(int i = lo + t; i < hi; i += 256)
    atomicAdd(&lh[(edgebuf[i] >> 16) & 255], 1);
  __syncthreads();
  int v = lh[t];
  sb[t] = v; __syncthreads();
  int acc = v;
  #pragma unroll
  for(int d = 1; d < 256; d <<= 1){
    int o = (t >= d) ? sb[t-d] : 0;
    __syncthreads();
    acc += o; sb[t] = acc;
    __syncthreads();
  }
  int excl = acc - v;
  lcur[t] = lo + excl;
  int node = b*256 + t;
  if(node < NNODES) rowptr[node] = lo + excl;
  __syncthreads();
  for(int i = lo + t; i < hi; i += 256){
    unsigned int p = edgebuf[i];
    int pos = atomicAdd(&lcur[(p >> 16) & 255], 1);
    esrc[pos] = (int)(p & 0xffffu);
  }
}

// ---------------- GEMM + attention-score epilogue ----------------
// Block: 64 rows x 128 cols. X staged ONCE (full K); W double-buffered in
// 32-k tiles with register prefetch -> ONE barrier per tile (vs 2x before).
// Lane tile 8 rows x 4 cols. LDS: K=128 -> 32+32=64KB (2 blk/CU); K=64 -> 48KB.
template<int K>
__global__ __launch_bounds__(256, 2) void gemm_att_kernel(
    const float* __restrict__ in, const float* __restrict__ W,
    const float* __restrict__ att_s, const float* __restrict__ att_d,
    __half2* __restrict__ h16, float* __restrict__ asrc, float* __restrict__ adst, int n)
{
  constexpr int NT = K/32;                      // K-tiles
  __shared__ __align__(16) float sX[64*K];      // 32KB (K=128) / 16KB (K=64)
  __shared__ __align__(16) float sW[2][32*128]; // 2x16KB
  int t = threadIdx.x;
  int row0 = blockIdx.x*64;
  int lane = t & 63;
  int c  = lane & 31;          // col-quad: cols 4c..4c+3 (c<16 head0, c>=16 head1)
  int rg = lane >> 5;
  int wave = t >> 6;
  int rbase = wave*16 + rg*8;  // wave covers 16 rows

  const float4* in4 = (const float4*)in;
  const float4* W4  = (const float4*)W;
  float4* sX4 = (float4*)sX;

  // stage X once (clamped flat index for the tail block; garbage rows are masked later)
  {
    const int maxi = n*(K/4) - 1;
    const int base = row0*(K/4);
    #pragma unroll
    for(int i = 0; i < (64*K/4)/256; i++){
      int idx = base + i*256 + t;
      if(idx > maxi) idx = maxi;
      sX4[i*256 + t] = in4[idx];
    }
  }
  // stage W tile 0 -> buf 0
  float4 wreg[4];
  #pragma unroll
  for(int i = 0; i < 4; i++) wreg[i] = W4[i*256 + t];
  {
    float4* sW0 = (float4*)sW[0];
    #pragma unroll
    for(int i = 0; i < 4; i++) sW0[i*256 + t] = wreg[i];
  }
  __syncthreads();

  float4 acc[8];
  #pragma unroll
  for(int r = 0; r < 8; r++) acc[r] = make_float4(0.f,0.f,0.f,0.f);

  for(int tile = 0; tile < NT; tile++){
    // prefetch next W tile into registers (in flight during compute)
    if(tile + 1 < NT){
      #pragma unroll
      for(int i = 0; i < 4; i++) wreg[i] = W4[(tile+1)*1024 + i*256 + t];
    }
    const float4* sWc = (const float4*)sW[tile & 1];
    #pragma unroll
    for(int kq = 0; kq < 8; kq++){
      float4 w0 = sWc[(kq*4+0)*32 + c];
      float4 w1 = sWc[(kq*4+1)*32 + c];
      float4 w2 = sWc[(kq*4+2)*32 + c];
      float4 w3 = sWc[(kq*4+3)*32 + c];
      #pragma unroll
      for(int r = 0; r < 8; r++){
        float4 xv = sX4[(rbase + r)*(K/4) + tile*8 + kq];   // broadcast
        acc[r].x = fmaf(xv.x, w0.x, acc[r].x);
        acc[r].y = fmaf(xv.x, w0.y, acc[r].y);
        acc[r].z = fmaf(xv.x, w0.z, acc[r].z);
        acc[r].w = fmaf(xv.x, w0.w, acc[r].w);
        acc[r].x = fmaf(xv.y, w1.x, acc[r].x);
        acc[r].y = fmaf(xv.y, w1.y, acc[r].y);
        acc[r].z = fmaf(xv.y, w1.z, acc[r].z);
        acc[r].w = fmaf(xv.y, w1.w, acc[r].w);
        acc[r].x = fmaf(xv.z, w2.x, acc[r].x);
        acc[r].y = fmaf(xv.z, w2.y, acc[r].y);
        acc[r].z = fmaf(xv.z, w2.z, acc[r].z);
        acc[r].w = fmaf(xv.z, w2.w, acc[r].w);
        acc[r].x = fmaf(xv.w, w3.x, acc[r].x);
        acc[r].y = fmaf(xv.w, w3.y, acc[r].y);
        acc[r].z = fmaf(xv.w, w3.z, acc[r].z);
        acc[r].w = fmaf(xv.w, w3.w, acc[r].w);
      }
    }
    // write prefetched tile into the idle buffer (readers of it passed the last barrier)
    if(tile + 1 < NT){
      float4* sWn = (float4*)sW[(tile+1) & 1];
      #pragma unroll
      for(int i = 0; i < 4; i++) sWn[i*256 + t] = wreg[i];
    }
    __syncthreads();
  }

  float4 as4 = ((const float4*)att_s)[c];
  float4 ad4 = ((const float4*)att_d)[c];
  #pragma unroll
  for(int r = 0; r < 8; r++){
    int row = row0 + rbase + r;
    bool ok = row < n;
    if(ok){
      __half2 p0 = __float22half2_rn(make_float2(acc[r].x, acc[r].y));
      __half2 p1 = __float22half2_rn(make_float2(acc[r].z, acc[r].w));
      uint2 pk;
      pk.x = *(unsigned int*)&p0;
      pk.y = *(unsigned int*)&p1;
      ((uint2*)h16)[(size_t)row*32 + c] = pk;
    }
    float ps = acc[r].x*as4.x + acc[r].y*as4.y + acc[r].z*as4.z + acc[r].w*as4.w;
    float pd = acc[r].x*ad4.x + acc[r].y*ad4.y + acc[r].z*ad4.z + acc[r].w*ad4.w;
    #pragma unroll
    for(int m = 1; m < 16; m <<= 1){ ps += __shfl_xor(ps, m); pd += __shfl_xor(pd, m); }
    if(ok && (c & 15) == 0){
      int head = c >> 4;
      asrc[2*row + head] = ps;
      adst[2*row + head] = pd;
    }
  }
}

// ---------------- softmax + aggregation: 4 nodes/wave, 16 lanes/node ----------------
template<int LAYER>
__global__ __launch_bounds__(256) void aggregate_kernel(
    const uint4* __restrict__ h16u4, const float2* __restrict__ asrc2, const float2* __restrict__ adst2,
    const int* __restrict__ rowptr, const int* __restrict__ esrc,
    const float* __restrict__ bias, const float* __restrict__ fcW, const float* __restrict__ fcb,
    float* __restrict__ out, int n)
{
  __shared__ float4 sE[16][CAP+1];
  int t = threadIdx.x;
  int p = t & 15;
  int slot = t >> 4;
  int node = blockIdx.x*16 + slot;
  bool valid = node < n;
  int nd = valid ? node : 0;
  int beg = rowptr[nd], end = rowptr[nd+1];
  if(!valid){ beg = 0; end = 0; }
  float2 adn = adst2[nd];

  float s0 = 0.f, s1 = 0.f;
  for(int i = beg + p; i < end; i += 16){
    int s = esrc[i];
    float2 av = asrc2[s];
    float e0 = av.x + adn.x; e0 = (e0 > 0.f) ? e0 : 0.2f*e0;
    float e1 = av.y + adn.y; e1 = (e1 > 0.f) ? e1 : 0.2f*e1;
    float w0 = __expf(e0), w1 = __expf(e1);
    s0 += w0; s1 += w1;
    int j = i - beg;
    if(j < CAP) sE[slot][j] = make_float4(w0, w1, __int_as_float(s), 0.f);
  }
  #pragma unroll
  for(int m = 1; m < 16; m <<= 1){ s0 += __shfl_xor(s0, m); s1 += __shfl_xor(s1, m); }
  float inv0 = 1.f/(s0 + 1e-16f), inv1 = 1.f/(s1 + 1e-16f);

  int deg = end - beg;
  int dcap = deg < CAP ? deg : CAP;
  for(int j = p; j < dcap; j += 16){
    float4 e = sE[slot][j];
    e.x *= inv0; e.y *= inv1;
    sE[slot][j] = e;
  }
  int maxd = dcap;
  maxd = max(maxd, __shfl_xor(maxd, 16));
  maxd = max(maxd, __shfl_xor(maxd, 32));

  bool head1 = p >= 8;
  float2 acc0 = make_float2(0.f,0.f), acc1 = acc0, acc2 = acc0, acc3 = acc0;

  #pragma unroll 4
  for(int j = 0; j < maxd; j++){
    float4 e = sE[slot][j];
    bool act = j < dcap;
    float alpha = act ? (head1 ? e.y : e.x) : 0.f;
    int s = act ? __float_as_int(e.z) : 0;
    uint4 hv = h16u4[(size_t)s*16 + p];
    const __half2 h0 = *(const __half2*)&hv.x;
    const __half2 h1 = *(const __half2*)&hv.y;
    const __half2 h2 = *(const __half2*)&hv.z;
    const __half2 h3 = *(const __half2*)&hv.w;
    acc0.x = fmaf(__half2float(h0.x), alpha, acc0.x);
    acc0.y = fmaf(__half2float(h0.y), alpha, acc0.y);
    acc1.x = fmaf(__half2float(h1.x), alpha, acc1.x);
    acc1.y = fmaf(__half2float(h1.y), alpha, acc1.y);
    acc2.x = fmaf(__half2float(h2.x), alpha, acc2.x);
    acc2.y = fmaf(__half2float(h2.y), alpha, acc2.y);
    acc3.x = fmaf(__half2float(h3.x), alpha, acc3.x);
    acc3.y = fmaf(__half2float(h3.y), alpha, acc3.y);
  }
  float inv_mine = head1 ? inv1 : inv0;
  float adh = head1 ? adn.y : adn.x;
  for(int i2 = beg + CAP; i2 < end; i2++){
    int s = esrc[i2];
    float2 av = asrc2[s];
    float e_ = (head1 ? av.y : av.x) + adh;
    e_ = (e_ > 0.f) ? e_ : 0.2f*e_;
    float alpha = __expf(e_) * inv_mine;
    uint4 hv = h16u4[(size_t)s*16 + p];
    const __half2 h0 = *(const __half2*)&hv.x;
    const __half2 h1 = *(const __half2*)&hv.y;
    const __half2 h2 = *(const __half2*)&hv.z;
    const __half2 h3 = *(const __half2*)&hv.w;
    acc0.x = fmaf(__half2float(h0.x), alpha, acc0.x);
    acc0.y = fmaf(__half2float(h0.y), alpha, acc0.y);
    acc1.x = fmaf(__half2float(h1.x), alpha, acc1.x);
    acc1.y = fmaf(__half2float(h1.y), alpha, acc1.y);
    acc2.x = fmaf(__half2float(h2.x), alpha, acc2.x);
    acc2.y = fmaf(__half2float(h2.y), alpha, acc2.y);
    acc3.x = fmaf(__half2float(h3.x), alpha, acc3.x);
    acc3.y = fmaf(__half2float(h3.y), alpha, acc3.y);
  }

  float o0 = acc0.x + __shfl_xor(acc0.x, 8);
  float o1 = acc0.y + __shfl_xor(acc0.y, 8);
  float o2 = acc1.x + __shfl_xor(acc1.x, 8);
  float o3 = acc1.y + __shfl_xor(acc1.y, 8);
  float o4 = acc2.x + __shfl_xor(acc2.x, 8);
  float o5 = acc2.y + __shfl_xor(acc2.y, 8);
  float o6 = acc3.x + __shfl_xor(acc3.x, 8);
  float o7 = acc3.y + __shfl_xor(acc3.y, 8);

  if(LAYER == 1){
    if(!head1 && valid){
      float4 b0 = ((const float4*)bias)[2*p];
      float4 b1 = ((const float4*)bias)[2*p+1];
      float4 r0 = make_float4(fmaxf(fmaf(0.5f,o0,b0.x),0.f), fmaxf(fmaf(0.5f,o1,b0.y),0.f),
                              fmaxf(fmaf(0.5f,o2,b0.z),0.f), fmaxf(fmaf(0.5f,o3,b0.w),0.f));
      float4 r1 = make_float4(fmaxf(fmaf(0.5f,o4,b1.x),0.f), fmaxf(fmaf(0.5f,o5,b1.y),0.f),
                              fmaxf(fmaf(0.5f,o6,b1.z),0.f), fmaxf(fmaf(0.5f,o7,b1.w),0.f));
      float4* orow = (float4*)(out + (size_t)node*64 + 8*p);
      orow[0] = r0; orow[1] = r1;
    }
  } else {
    float partial = 0.f;
    if(!head1){
      float4 b0 = ((const float4*)bias)[2*p];
      float4 b1 = ((const float4*)bias)[2*p+1];
      float4 w0 = ((const float4*)fcW)[2*p];
      float4 w1 = ((const float4*)fcW)[2*p+1];
      partial  = fmaxf(fmaf(0.5f,o0,b0.x),0.f)*w0.x + fmaxf(fmaf(0.5f,o1,b0.y),0.f)*w0.y
               + fmaxf(fmaf(0.5f,o2,b0.z),0.f)*w0.z + fmaxf(fmaf(0.5f,o3,b0.w),0.f)*w0.w
               + fmaxf(fmaf(0.5f,o4,b1.x),0.f)*w1.x + fmaxf(fmaf(0.5f,o5,b1.y),0.f)*w1.y
               + fmaxf(fmaf(0.5f,o6,b1.z),0.f)*w1.z + fmaxf(fmaf(0.5f,o7,b1.w),0.f)*w1.w;
    }
    partial += __shfl_xor(partial, 1);
    partial += __shfl_xor(partial, 2);
    partial += __shfl_xor(partial, 4);
    if(p == 0 && valid) out[node] = partial + fcb[0];
  }
}

// ---------------- launch ----------------
extern "C" void kernel_launch(void* const* d_in, const int* in_sizes, int n_in,
                              void* d_out, int out_size, void* d_ws, size_t ws_size,
                              hipStream_t stream)
{
  const float* x   = (const float*)d_in[0];
  const int*   ei  = (const int*)  d_in[1];
  const float* W1  = (const float*)d_in[2];
  const float* as1 = (const float*)d_in[3];
  const float* ad1 = (const float*)d_in[4];
  const float* b1  = (const float*)d_in[5];
  const float* W2  = (const float*)d_in[6];
  const float* as2 = (const float*)d_in[7];
  const float* ad2 = (const float*)d_in[8];
  const float* b2  = (const float*)d_in[9];
  const float* fcW = (const float*)d_in[10];
  const float* fcb = (const float*)d_in[11];
  float* out = (float*)d_out;

  char* ws = (char*)d_ws;
  size_t off = 0;
  auto alloc = [&](size_t bytes) -> void* {
    void* p = ws + off;
    off += (bytes + 255) & ~(size_t)255;
    return p;
  };
  int*          rowptr      = (int*)         alloc((NNODES+1)*sizeof(int));
  int*          bucketHist  = (int*)         alloc(NB*sizeof(int));
  int*          bucketBase  = (int*)         alloc((NB+1)*sizeof(int));
  int*          bucketCursor= (int*)         alloc(NB*sizeof(int));
  unsigned int* edgebuf     = (unsigned int*)alloc((size_t)EP*sizeof(unsigned int));
  int*          esrc        = (int*)         alloc((size_t)EP*sizeof(int));
  __half2*      h16         = (__half2*)     alloc((size_t)NNODES*64*sizeof(__half2));
  float*        asrc        = (float*)       alloc((size_t)NNODES*2*sizeof(float));
  float*        adst        = (float*)       alloc((size_t)NNODES*2*sizeof(float));
  float*        out1        = (float*)       alloc((size_t)NNODES*64*sizeof(float));

  const int nchunks = (EP + CHUNK - 1)/CHUNK;   // 104

  hipMemsetAsync(bucketHist, 0, NB*sizeof(int), stream);
  hipLaunchKernelGGL(bucket_hist_kernel, dim3(nchunks), dim3(256), 0, stream, ei, bucketHist);
  hipLaunchKernelGGL(bucket_scan_kernel, dim3(1),       dim3(256), 0, stream, bucketHist, bucketBase, bucketCursor, rowptr);
  hipLaunchKernelGGL(partition_kernel,   dim3(nchunks), dim3(256), 0, stream, ei, bucketCursor, edgebuf);
  hipLaunchKernelGGL(bucket_sort_kernel, dim3(NB),      dim3(256), 0, stream, edgebuf, bucketBase, rowptr, esrc);

  hipLaunchKernelGGL((gemm_att_kernel<128>), dim3((NNODES+63)/64), dim3(256), 0, stream,
                     x, W1, as1, ad1, h16, asrc, adst, NNODES);
  hipLaunchKernelGGL((aggregate_kernel<1>),  dim3((NNODES+15)/16), dim3(256), 0, stream,
                     (const uint4*)h16, (const float2*)asrc, (const float2*)adst, rowptr, esrc,
                     b1, (const float*)nullptr, (const float*)nullptr, out1, NNODES);
  hipLaunchKernelGGL((gemm_att_kernel<64>),  dim3((NNODES+63)/64), dim3(256), 0, stream,
                     out1, W2, as2, ad2, h16, asrc, adst, NNODES);
  hipLaunchKernelGGL((aggregate_kernel<2>),  dim3((NNODES+15)/16), dim3(256), 0, stream,
                     (const uint4*)h16, (const float2*)asrc, (const float2*)adst, rowptr, esrc,
                     b2, fcW, fcb, out, NNODES);
}

// Round 7
// 248.228 us; speedup vs baseline: 2.1348x; 2.1348x over previous
//
#include <hip/hip_runtime.h>
#include <hip/hip_fp16.h>

#define NNODES 50000
#define NEDGES 800000
#define EP (NEDGES + NNODES)   // 850000 edges incl. self-loops
#define CAP 64                 // per-node LDS edge cache in aggregate
#define NB 196                 // dst buckets of 256 nodes: ceil(50000/256)
#define CHUNK 8192             // edges per partition block

// ---------------- CSR build: two-level counting sort ----------------
__global__ __launch_bounds__(256) void bucket_hist_kernel(const int* __restrict__ ei, int* __restrict__ bucketHist){
  __shared__ int lh[NB];
  int t = threadIdx.x;
  for(int i = t; i < NB; i += 256) lh[i] = 0;
  __syncthreads();
  int base = blockIdx.x*CHUNK;
  #pragma unroll
  for(int k = 0; k < CHUNK; k += 256){
    int e = base + k + t;
    if(e < EP){
      int d = (e < NEDGES) ? ei[NEDGES + e] : (e - NEDGES);
      atomicAdd(&lh[d >> 8], 1);
    }
  }
  __syncthreads();
  for(int i = t; i < NB; i += 256) if(lh[i]) atomicAdd(&bucketHist[i], lh[i]);
}

__global__ __launch_bounds__(256) void bucket_scan_kernel(const int* __restrict__ bucketHist,
                                                          int* __restrict__ bucketBase,
                                                          int* __restrict__ bucketCursor,
                                                          int* __restrict__ rowptr){
  __shared__ int sb[256];
  int t = threadIdx.x;
  int v = (t < NB) ? bucketHist[t] : 0;
  sb[t] = v; __syncthreads();
  int acc = v;
  #pragma unroll
  for(int d = 1; d < 256; d <<= 1){
    int o = (t >= d) ? sb[t-d] : 0;
    __syncthreads();
    acc += o; sb[t] = acc;
    __syncthreads();
  }
  int excl = acc - v;
  if(t <= NB) bucketBase[t] = excl;
  if(t <  NB) bucketCursor[t] = excl;
  if(t == 0)  rowptr[NNODES] = EP;
}

__global__ __launch_bounds__(256) void partition_kernel(const int* __restrict__ ei,
                                                        int* __restrict__ bucketCursor,
                                                        unsigned int* __restrict__ edgebuf){
  __shared__ unsigned int stage[CHUNK];      // 32 KB
  __shared__ int lh[NB], lbase[NB], lcur[NB], gbase[NB];
  __shared__ int sb[256];
  int t = threadIdx.x;
  for(int i = t; i < NB; i += 256) lh[i] = 0;
  __syncthreads();
  int base = blockIdx.x*CHUNK;
  unsigned int pk[CHUNK/256];
  #pragma unroll
  for(int k = 0; k < CHUNK/256; k++){
    int e = base + k*256 + t;
    unsigned int p = 0xffffffffu;
    if(e < EP){
      int s, d;
      if(e < NEDGES){ s = ei[e]; d = ei[NEDGES + e]; }
      else          { s = d = e - NEDGES; }
      p = ((unsigned int)d << 16) | (unsigned int)s;
      atomicAdd(&lh[d >> 8], 1);
    }
    pk[k] = p;
  }
  __syncthreads();
  int v = (t < NB) ? lh[t] : 0;
  sb[t] = v; __syncthreads();
  int acc = v;
  #pragma unroll
  for(int d = 1; d < 256; d <<= 1){
    int o = (t >= d) ? sb[t-d] : 0;
    __syncthreads();
    acc += o; sb[t] = acc;
    __syncthreads();
  }
  int excl = acc - v;
  if(t < NB){
    lbase[t] = excl; lcur[t] = excl;
    gbase[t] = v ? atomicAdd(&bucketCursor[t], v) : 0;
  }
  __syncthreads();
  #pragma unroll
  for(int k = 0; k < CHUNK/256; k++){
    unsigned int p = pk[k];
    if(p != 0xffffffffu){
      int bin = p >> 24;
      int r = atomicAdd(&lcur[bin], 1);
      stage[r] = p;
    }
  }
  __syncthreads();
  int nvalid = EP - base; if(nvalid > CHUNK) nvalid = CHUNK;
  for(int j = t; j < nvalid; j += 256){
    unsigned int p = stage[j];
    int bin = p >> 24;
    edgebuf[gbase[bin] + (j - lbase[bin])] = p;
  }
}

__global__ __launch_bounds__(256) void bucket_sort_kernel(const unsigned int* __restrict__ edgebuf,
                                                          const int* __restrict__ bucketBase,
                                                          int* __restrict__ rowptr,
                                                          int* __restrict__ esrc){
  __shared__ int lh[256], lcur[256], sb[256];
  int b = blockIdx.x, t = threadIdx.x;
  int lo = bucketBase[b], hi = bucketBase[b+1];
  lh[t] = 0;
  __syncthreads();
  for(int i = lo + t; i < hi; i += 256)
    atomicAdd(&lh[(edgebuf[i] >> 16) & 255], 1);
  __syncthreads();
  int v = lh[t];
  sb[t] = v; __syncthreads();
  int acc = v;
  #pragma unroll
  for(int d = 1; d < 256; d <<= 1){
    int o = (t >= d) ? sb[t-d] : 0;
    __syncthreads();
    acc += o; sb[t] = acc;
    __syncthreads();
  }
  int excl = acc - v;
  lcur[t] = lo + excl;
  int node = b*256 + t;
  if(node < NNODES) rowptr[node] = lo + excl;
  __syncthreads();
  for(int i = lo + t; i < hi; i += 256){
    unsigned int p = edgebuf[i];
    int pos = atomicAdd(&lcur[(p >> 16) & 255], 1);
    esrc[pos] = (int)(p & 0xffffu);
  }
}

// ---------------- GEMM + attention-score epilogue ----------------
// REVERTED to the round-4 structure (benched 250us total): 64 rows x 128 cols,
// K-tiles of 32, per-tile W+X staging, 2 barriers/tile, 24KB LDS, VGPR ~72.
// (Round-6 W-double-buffer regressed 10x: register spill -> 860MB scratch traffic.)
template<int K>
__global__ __launch_bounds__(256, 4) void gemm_att_kernel(
    const float* __restrict__ in, const float* __restrict__ W,
    const float* __restrict__ att_s, const float* __restrict__ att_d,
    __half2* __restrict__ h16, float* __restrict__ asrc, float* __restrict__ adst, int n)
{
  __shared__ __align__(16) float sW[32*128];   // 16 KB
  __shared__ __align__(16) float sX[64*32];    // 8 KB
  int t = threadIdx.x;
  int row0 = blockIdx.x*64;
  int lane = t & 63;
  int c  = lane & 31;          // col-quad: cols 4c..4c+3 (c<16 head0, c>=16 head1)
  int rg = lane >> 5;          // row subgroup within wave
  int wave = t >> 6;
  int rbase = wave*16 + rg*8;  // wave covers 16 rows

  float4 acc[8];
  #pragma unroll
  for(int r = 0; r < 8; r++) acc[r] = make_float4(0.f,0.f,0.f,0.f);

  for(int kt = 0; kt < K; kt += 32){
    // stage W[kt..kt+32][0..128] (4096 floats, coalesced)
    {
      const float4* W4 = (const float4*)(W + (size_t)kt*128);
      float4* sW4 = (float4*)sW;
      #pragma unroll
      for(int i = 0; i < 4; i++) sW4[t + i*256] = W4[t + i*256];
    }
    // stage X rows row0..row0+64, k kt..kt+32 (512 float4)
    {
      float4* sX4 = (float4*)sX;
      #pragma unroll
      for(int i = 0; i < 2; i++){
        int idx = t + i*256;
        int r = idx >> 3, j = idx & 7;
        int grow = row0 + r;
        float4 v = make_float4(0.f,0.f,0.f,0.f);
        if(grow < n) v = ((const float4*)(in + (size_t)grow*K + kt))[j];
        sX4[idx] = v;
      }
    }
    __syncthreads();
    const float4* sW4 = (const float4*)sW;
    const float4* sX4 = (const float4*)sX;
    #pragma unroll
    for(int kq = 0; kq < 8; kq++){
      float4 w0 = sW4[(kq*4+0)*32 + c];
      float4 w1 = sW4[(kq*4+1)*32 + c];
      float4 w2 = sW4[(kq*4+2)*32 + c];
      float4 w3 = sW4[(kq*4+3)*32 + c];
      #pragma unroll
      for(int r = 0; r < 8; r++){
        float4 xv = sX4[(rbase + r)*8 + kq];   // 32-lane broadcast
        acc[r].x = fmaf(xv.x, w0.x, acc[r].x);
        acc[r].y = fmaf(xv.x, w0.y, acc[r].y);
        acc[r].z = fmaf(xv.x, w0.z, acc[r].z);
        acc[r].w = fmaf(xv.x, w0.w, acc[r].w);
        acc[r].x = fmaf(xv.y, w1.x, acc[r].x);
        acc[r].y = fmaf(xv.y, w1.y, acc[r].y);
        acc[r].z = fmaf(xv.y, w1.z, acc[r].z);
        acc[r].w = fmaf(xv.y, w1.w, acc[r].w);
        acc[r].x = fmaf(xv.z, w2.x, acc[r].x);
        acc[r].y = fmaf(xv.z, w2.y, acc[r].y);
        acc[r].z = fmaf(xv.z, w2.z, acc[r].z);
        acc[r].w = fmaf(xv.z, w2.w, acc[r].w);
        acc[r].x = fmaf(xv.w, w3.x, acc[r].x);
        acc[r].y = fmaf(xv.w, w3.y, acc[r].y);
        acc[r].z = fmaf(xv.w, w3.z, acc[r].z);
        acc[r].w = fmaf(xv.w, w3.w, acc[r].w);
      }
    }
    __syncthreads();
  }

  float4 as4 = ((const float4*)att_s)[c];
  float4 ad4 = ((const float4*)att_d)[c];
  #pragma unroll
  for(int r = 0; r < 8; r++){
    int row = row0 + rbase + r;
    bool ok = row < n;
    if(ok){
      __half2 p0 = __float22half2_rn(make_float2(acc[r].x, acc[r].y));
      __half2 p1 = __float22half2_rn(make_float2(acc[r].z, acc[r].w));
      uint2 pk;
      pk.x = *(unsigned int*)&p0;
      pk.y = *(unsigned int*)&p1;
      ((uint2*)h16)[(size_t)row*32 + c] = pk;
    }
    float ps = acc[r].x*as4.x + acc[r].y*as4.y + acc[r].z*as4.z + acc[r].w*as4.w;
    float pd = acc[r].x*ad4.x + acc[r].y*ad4.y + acc[r].z*ad4.z + acc[r].w*ad4.w;
    #pragma unroll
    for(int m = 1; m < 16; m <<= 1){ ps += __shfl_xor(ps, m); pd += __shfl_xor(pd, m); }
    if(ok && (c & 15) == 0){
      int head = c >> 4;
      asrc[2*row + head] = ps;
      adst[2*row + head] = pd;
    }
  }
}

// ---------------- softmax + aggregation: 4 nodes/wave, 16 lanes/node ----------------
template<int LAYER>
__global__ __launch_bounds__(256) void aggregate_kernel(
    const uint4* __restrict__ h16u4, const float2* __restrict__ asrc2, const float2* __restrict__ adst2,
    const int* __restrict__ rowptr, const int* __restrict__ esrc,
    const float* __restrict__ bias, const float* __restrict__ fcW, const float* __restrict__ fcb,
    float* __restrict__ out, int n)
{
  __shared__ float4 sE[16][CAP+1];
  int t = threadIdx.x;
  int p = t & 15;
  int slot = t >> 4;
  int node = blockIdx.x*16 + slot;
  bool valid = node < n;
  int nd = valid ? node : 0;
  int beg = rowptr[nd], end = rowptr[nd+1];
  if(!valid){ beg = 0; end = 0; }
  float2 adn = adst2[nd];

  float s0 = 0.f, s1 = 0.f;
  for(int i = beg + p; i < end; i += 16){
    int s = esrc[i];
    float2 av = asrc2[s];
    float e0 = av.x + adn.x; e0 = (e0 > 0.f) ? e0 : 0.2f*e0;
    float e1 = av.y + adn.y; e1 = (e1 > 0.f) ? e1 : 0.2f*e1;
    float w0 = __expf(e0), w1 = __expf(e1);
    s0 += w0; s1 += w1;
    int j = i - beg;
    if(j < CAP) sE[slot][j] = make_float4(w0, w1, __int_as_float(s), 0.f);
  }
  #pragma unroll
  for(int m = 1; m < 16; m <<= 1){ s0 += __shfl_xor(s0, m); s1 += __shfl_xor(s1, m); }
  float inv0 = 1.f/(s0 + 1e-16f), inv1 = 1.f/(s1 + 1e-16f);

  int deg = end - beg;
  int dcap = deg < CAP ? deg : CAP;
  for(int j = p; j < dcap; j += 16){
    float4 e = sE[slot][j];
    e.x *= inv0; e.y *= inv1;
    sE[slot][j] = e;
  }
  int maxd = dcap;
  maxd = max(maxd, __shfl_xor(maxd, 16));
  maxd = max(maxd, __shfl_xor(maxd, 32));

  bool head1 = p >= 8;
  float2 acc0 = make_float2(0.f,0.f), acc1 = acc0, acc2 = acc0, acc3 = acc0;

  #pragma unroll 4
  for(int j = 0; j < maxd; j++){
    float4 e = sE[slot][j];
    bool act = j < dcap;
    float alpha = act ? (head1 ? e.y : e.x) : 0.f;
    int s = act ? __float_as_int(e.z) : 0;
    uint4 hv = h16u4[(size_t)s*16 + p];
    const __half2 h0 = *(const __half2*)&hv.x;
    const __half2 h1 = *(const __half2*)&hv.y;
    const __half2 h2 = *(const __half2*)&hv.z;
    const __half2 h3 = *(const __half2*)&hv.w;
    acc0.x = fmaf(__half2float(h0.x), alpha, acc0.x);
    acc0.y = fmaf(__half2float(h0.y), alpha, acc0.y);
    acc1.x = fmaf(__half2float(h1.x), alpha, acc1.x);
    acc1.y = fmaf(__half2float(h1.y), alpha, acc1.y);
    acc2.x = fmaf(__half2float(h2.x), alpha, acc2.x);
    acc2.y = fmaf(__half2float(h2.y), alpha, acc2.y);
    acc3.x = fmaf(__half2float(h3.x), alpha, acc3.x);
    acc3.y = fmaf(__half2float(h3.y), alpha, acc3.y);
  }
  float inv_mine = head1 ? inv1 : inv0;
  float adh = head1 ? adn.y : adn.x;
  for(int i2 = beg + CAP; i2 < end; i2++){
    int s = esrc[i2];
    float2 av = asrc2[s];
    float e_ = (head1 ? av.y : av.x) + adh;
    e_ = (e_ > 0.f) ? e_ : 0.2f*e_;
    float alpha = __expf(e_) * inv_mine;
    uint4 hv = h16u4[(size_t)s*16 + p];
    const __half2 h0 = *(const __half2*)&hv.x;
    const __half2 h1 = *(const __half2*)&hv.y;
    const __half2 h2 = *(const __half2*)&hv.z;
    const __half2 h3 = *(const __half2*)&hv.w;
    acc0.x = fmaf(__half2float(h0.x), alpha, acc0.x);
    acc0.y = fmaf(__half2float(h0.y), alpha, acc0.y);
    acc1.x = fmaf(__half2float(h1.x), alpha, acc1.x);
    acc1.y = fmaf(__half2float(h1.y), alpha, acc1.y);
    acc2.x = fmaf(__half2float(h2.x), alpha, acc2.x);
    acc2.y = fmaf(__half2float(h2.y), alpha, acc2.y);
    acc3.x = fmaf(__half2float(h3.x), alpha, acc3.x);
    acc3.y = fmaf(__half2float(h3.y), alpha, acc3.y);
  }

  float o0 = acc0.x + __shfl_xor(acc0.x, 8);
  float o1 = acc0.y + __shfl_xor(acc0.y, 8);
  float o2 = acc1.x + __shfl_xor(acc1.x, 8);
  float o3 = acc1.y + __shfl_xor(acc1.y, 8);
  float o4 = acc2.x + __shfl_xor(acc2.x, 8);
  float o5 = acc2.y + __shfl_xor(acc2.y, 8);
  float o6 = acc3.x + __shfl_xor(acc3.x, 8);
  float o7 = acc3.y + __shfl_xor(acc3.y, 8);

  if(LAYER == 1){
    if(!head1 && valid){
      float4 b0 = ((const float4*)bias)[2*p];
      float4 b1 = ((const float4*)bias)[2*p+1];
      float4 r0 = make_float4(fmaxf(fmaf(0.5f,o0,b0.x),0.f), fmaxf(fmaf(0.5f,o1,b0.y),0.f),
                              fmaxf(fmaf(0.5f,o2,b0.z),0.f), fmaxf(fmaf(0.5f,o3,b0.w),0.f));
      float4 r1 = make_float4(fmaxf(fmaf(0.5f,o4,b1.x),0.f), fmaxf(fmaf(0.5f,o5,b1.y),0.f),
                              fmaxf(fmaf(0.5f,o6,b1.z),0.f), fmaxf(fmaf(0.5f,o7,b1.w),0.f));
      float4* orow = (float4*)(out + (size_t)node*64 + 8*p);
      orow[0] = r0; orow[1] = r1;
    }
  } else {
    float partial = 0.f;
    if(!head1){
      float4 b0 = ((const float4*)bias)[2*p];
      float4 b1 = ((const float4*)bias)[2*p+1];
      float4 w0 = ((const float4*)fcW)[2*p];
      float4 w1 = ((const float4*)fcW)[2*p+1];
      partial  = fmaxf(fmaf(0.5f,o0,b0.x),0.f)*w0.x + fmaxf(fmaf(0.5f,o1,b0.y),0.f)*w0.y
               + fmaxf(fmaf(0.5f,o2,b0.z),0.f)*w0.z + fmaxf(fmaf(0.5f,o3,b0.w),0.f)*w0.w
               + fmaxf(fmaf(0.5f,o4,b1.x),0.f)*w1.x + fmaxf(fmaf(0.5f,o5,b1.y),0.f)*w1.y
               + fmaxf(fmaf(0.5f,o6,b1.z),0.f)*w1.z + fmaxf(fmaf(0.5f,o7,b1.w),0.f)*w1.w;
    }
    partial += __shfl_xor(partial, 1);
    partial += __shfl_xor(partial, 2);
    partial += __shfl_xor(partial, 4);
    if(p == 0 && valid) out[node] = partial + fcb[0];
  }
}

// ---------------- launch ----------------
extern "C" void kernel_launch(void* const* d_in, const int* in_sizes, int n_in,
                              void* d_out, int out_size, void* d_ws, size_t ws_size,
                              hipStream_t stream)
{
  const float* x   = (const float*)d_in[0];
  const int*   ei  = (const int*)  d_in[1];
  const float* W1  = (const float*)d_in[2];
  const float* as1 = (const float*)d_in[3];
  const float* ad1 = (const float*)d_in[4];
  const float* b1  = (const float*)d_in[5];
  const float* W2  = (const float*)d_in[6];
  const float* as2 = (const float*)d_in[7];
  const float* ad2 = (const float*)d_in[8];
  const float* b2  = (const float*)d_in[9];
  const float* fcW = (const float*)d_in[10];
  const float* fcb = (const float*)d_in[11];
  float* out = (float*)d_out;

  char* ws = (char*)d_ws;
  size_t off = 0;
  auto alloc = [&](size_t bytes) -> void* {
    void* p = ws + off;
    off += (bytes + 255) & ~(size_t)255;
    return p;
  };
  int*          rowptr      = (int*)         alloc((NNODES+1)*sizeof(int));
  int*          bucketHist  = (int*)         alloc(NB*sizeof(int));
  int*          bucketBase  = (int*)         alloc((NB+1)*sizeof(int));
  int*          bucketCursor= (int*)         alloc(NB*sizeof(int));
  unsigned int* edgebuf     = (unsigned int*)alloc((size_t)EP*sizeof(unsigned int));
  int*          esrc        = (int*)         alloc((size_t)EP*sizeof(int));
  __half2*      h16         = (__half2*)     alloc((size_t)NNODES*64*sizeof(__half2));
  float*        asrc        = (float*)       alloc((size_t)NNODES*2*sizeof(float));
  float*        adst        = (float*)       alloc((size_t)NNODES*2*sizeof(float));
  float*        out1        = (float*)       alloc((size_t)NNODES*64*sizeof(float));

  const int nchunks = (EP + CHUNK - 1)/CHUNK;   // 104

  hipMemsetAsync(bucketHist, 0, NB*sizeof(int), stream);
  hipLaunchKernelGGL(bucket_hist_kernel, dim3(nchunks), dim3(256), 0, stream, ei, bucketHist);
  hipLaunchKernelGGL(bucket_scan_kernel, dim3(1),       dim3(256), 0, stream, bucketHist, bucketBase, bucketCursor, rowptr);
  hipLaunchKernelGGL(partition_kernel,   dim3(nchunks), dim3(256), 0, stream, ei, bucketCursor, edgebuf);
  hipLaunchKernelGGL(bucket_sort_kernel, dim3(NB),      dim3(256), 0, stream, edgebuf, bucketBase, rowptr, esrc);

  hipLaunchKernelGGL((gemm_att_kernel<128>), dim3((NNODES+63)/64), dim3(256), 0, stream,
                     x, W1, as1, ad1, h16, asrc, adst, NNODES);
  hipLaunchKernelGGL((aggregate_kernel<1>),  dim3((NNODES+15)/16), dim3(256), 0, stream,
                     (const uint4*)h16, (const float2*)asrc, (const float2*)adst, rowptr, esrc,
                     b1, (const float*)nullptr, (const float*)nullptr, out1, NNODES);
  hipLaunchKernelGGL((gemm_att_kernel<64>),  dim3((NNODES+63)/64), dim3(256), 0, stream,
                     out1, W2, as2, ad2, h16, asrc, adst, NNODES);
  hipLaunchKernelGGL((aggregate_kernel<2>),  dim3((NNODES+15)/16), dim3(256), 0, stream,
                     (const uint4*)h16, (const float2*)asrc, (const float2*)adst, rowptr, esrc,
                     b2, fcW, fcb, out, NNODES);
}

// Round 8
// 229.437 us; speedup vs baseline: 2.3097x; 1.0819x over previous
//
#include <hip/hip_runtime.h>
#include <hip/hip_fp16.h>

#define NNODES 50000
#define NEDGES 800000
#define EP (NEDGES + NNODES)   // 850000 edges incl. self-loops
#define CAP 64                 // per-node LDS edge cache in aggregate
#define NB 196                 // dst buckets of 256 nodes: ceil(50000/256)
#define CHUNK 8192             // edges per partition block

typedef _Float16 half8_t __attribute__((ext_vector_type(8)));
typedef float f32x4 __attribute__((ext_vector_type(4)));

// ---------------- CSR build: two-level counting sort ----------------
__global__ __launch_bounds__(256) void bucket_hist_kernel(const int* __restrict__ ei, int* __restrict__ bucketHist){
  __shared__ int lh[NB];
  int t = threadIdx.x;
  for(int i = t; i < NB; i += 256) lh[i] = 0;
  __syncthreads();
  int base = blockIdx.x*CHUNK;
  #pragma unroll
  for(int k = 0; k < CHUNK; k += 256){
    int e = base + k + t;
    if(e < EP){
      int d = (e < NEDGES) ? ei[NEDGES + e] : (e - NEDGES);
      atomicAdd(&lh[d >> 8], 1);
    }
  }
  __syncthreads();
  for(int i = t; i < NB; i += 256) if(lh[i]) atomicAdd(&bucketHist[i], lh[i]);
}

__global__ __launch_bounds__(256) void bucket_scan_kernel(const int* __restrict__ bucketHist,
                                                          int* __restrict__ bucketBase,
                                                          int* __restrict__ bucketCursor,
                                                          int* __restrict__ rowptr){
  __shared__ int sb[256];
  int t = threadIdx.x;
  int v = (t < NB) ? bucketHist[t] : 0;
  sb[t] = v; __syncthreads();
  int acc = v;
  #pragma unroll
  for(int d = 1; d < 256; d <<= 1){
    int o = (t >= d) ? sb[t-d] : 0;
    __syncthreads();
    acc += o; sb[t] = acc;
    __syncthreads();
  }
  int excl = acc - v;
  if(t <= NB) bucketBase[t] = excl;
  if(t <  NB) bucketCursor[t] = excl;
  if(t == 0)  rowptr[NNODES] = EP;
}

__global__ __launch_bounds__(256) void partition_kernel(const int* __restrict__ ei,
                                                        int* __restrict__ bucketCursor,
                                                        unsigned int* __restrict__ edgebuf){
  __shared__ unsigned int stage[CHUNK];      // 32 KB
  __shared__ int lh[NB], lbase[NB], lcur[NB], gbase[NB];
  __shared__ int sb[256];
  int t = threadIdx.x;
  for(int i = t; i < NB; i += 256) lh[i] = 0;
  __syncthreads();
  int base = blockIdx.x*CHUNK;
  unsigned int pk[CHUNK/256];
  #pragma unroll
  for(int k = 0; k < CHUNK/256; k++){
    int e = base + k*256 + t;
    unsigned int p = 0xffffffffu;
    if(e < EP){
      int s, d;
      if(e < NEDGES){ s = ei[e]; d = ei[NEDGES + e]; }
      else          { s = d = e - NEDGES; }
      p = ((unsigned int)d << 16) | (unsigned int)s;
      atomicAdd(&lh[d >> 8], 1);
    }
    pk[k] = p;
  }
  __syncthreads();
  int v = (t < NB) ? lh[t] : 0;
  sb[t] = v; __syncthreads();
  int acc = v;
  #pragma unroll
  for(int d = 1; d < 256; d <<= 1){
    int o = (t >= d) ? sb[t-d] : 0;
    __syncthreads();
    acc += o; sb[t] = acc;
    __syncthreads();
  }
  int excl = acc - v;
  if(t < NB){
    lbase[t] = excl; lcur[t] = excl;
    gbase[t] = v ? atomicAdd(&bucketCursor[t], v) : 0;
  }
  __syncthreads();
  #pragma unroll
  for(int k = 0; k < CHUNK/256; k++){
    unsigned int p = pk[k];
    if(p != 0xffffffffu){
      int bin = p >> 24;
      int r = atomicAdd(&lcur[bin], 1);
      stage[r] = p;
    }
  }
  __syncthreads();
  int nvalid = EP - base; if(nvalid > CHUNK) nvalid = CHUNK;
  for(int j = t; j < nvalid; j += 256){
    unsigned int p = stage[j];
    int bin = p >> 24;
    edgebuf[gbase[bin] + (j - lbase[bin])] = p;
  }
}

__global__ __launch_bounds__(256) void bucket_sort_kernel(const unsigned int* __restrict__ edgebuf,
                                                          const int* __restrict__ bucketBase,
                                                          int* __restrict__ rowptr,
                                                          int* __restrict__ esrc){
  __shared__ int lh[256], lcur[256], sb[256];
  int b = blockIdx.x, t = threadIdx.x;
  int lo = bucketBase[b], hi = bucketBase[b+1];
  lh[t] = 0;
  __syncthreads();
  for(int i = lo + t; i < hi; i += 256)
    atomicAdd(&lh[(edgebuf[i] >> 16) & 255], 1);
  __syncthreads();
  int v = lh[t];
  sb[t] = v; __syncthreads();
  int acc = v;
  #pragma unroll
  for(int d = 1; d < 256; d <<= 1){
    int o = (t >= d) ? sb[t-d] : 0;
    __syncthreads();
    acc += o; sb[t] = acc;
    __syncthreads();
  }
  int excl = acc - v;
  lcur[t] = lo + excl;
  int node = b*256 + t;
  if(node < NNODES) rowptr[node] = lo + excl;
  __syncthreads();
  for(int i = lo + t; i < hi; i += 256){
    unsigned int p = edgebuf[i];
    int pos = atomicAdd(&lcur[(p >> 16) & 255], 1);
    esrc[pos] = (int)(p & 0xffffu);
  }
}

// ---------------- W transpose+fp16 convert (one-time) ----------------
// Wt1[n][128] = fp16(W1[k][n]); Wt2[n][64] = fp16(W2[k][n])
__global__ __launch_bounds__(256) void transpose_w_kernel(const float* __restrict__ W1,
                                                          const float* __restrict__ W2,
                                                          __half* __restrict__ Wt1,
                                                          __half* __restrict__ Wt2){
  int t = blockIdx.x*256 + threadIdx.x;
  if(t < 16384){
    int k = t >> 7, nn = t & 127;
    Wt1[nn*128 + k] = __float2half(W1[t]);
  } else if(t < 16384 + 8192){
    int i = t - 16384;
    int k = i >> 7, nn = i & 127;
    Wt2[nn*64 + k] = __float2half(W2[i]);
  }
}

// ---------------- MFMA GEMM + attention-score epilogue ----------------
// Block: 64 rows x 128 cols, whole K staged ONCE (x fp32->fp16 cvt + Wt fp16),
// ONE barrier, then 8 col-tiles x (K/32) k-steps of mfma_f32_16x16x32_f16.
// A[m=lane&15][k=quad*8+j] from sX row; B[k][n=lane&15] from sW row (Wt layout).
// C/D: col=lane&15, row=quad*4+reg (guide §3, m89-verified).
template<int K>
__global__ __launch_bounds__(256, 3) void gemm_att_kernel(
    const float* __restrict__ in, const __half* __restrict__ Wt,
    const float* __restrict__ att_s, const float* __restrict__ att_d,
    __half2* __restrict__ h16, float* __restrict__ asrc, float* __restrict__ adst, int n)
{
  constexpr int KP = K + 8;                 // fp16 row stride: 16B-aligned, 4-bank row shift
  constexpr int NKS = K/32;                 // k-steps
  __shared__ __align__(16) __half sX[64*KP];
  __shared__ __align__(16) __half sW[128*KP];
  int t = threadIdx.x;
  int row0 = blockIdx.x*64;

  // stage X (cvt fp32->fp16), clamped flat index for tail block (masked on store)
  {
    const float4* in4 = (const float4*)in;
    const int nf4 = 64*K/4;
    const int maxi = n*(K/4) - 1;
    for(int i = t; i < nf4; i += 256){
      int r = i/(K/4), j = i%(K/4);
      int gi = row0*(K/4) + i;
      if(gi > maxi) gi = maxi;
      float4 v = in4[gi];
      __half2 p0 = __floats2half2_rn(v.x, v.y);
      __half2 p1 = __floats2half2_rn(v.z, v.w);
      uint2 pk;
      pk.x = *(unsigned int*)&p0;
      pk.y = *(unsigned int*)&p1;
      *(uint2*)&sX[r*KP + j*4] = pk;
    }
  }
  // stage Wt (already fp16, [128][K] dense), uint4 = 8 fp16
  {
    const uint4* Wt4 = (const uint4*)Wt;
    const int nw = 128*K/8;
    for(int i = t; i < nw; i += 256){
      int r = i/(K/8), j = i%(K/8);
      *(uint4*)&sW[r*KP + j*8] = Wt4[i];
    }
  }
  __syncthreads();

  int lane = t & 63;
  int l15  = lane & 15;
  int quad = lane >> 4;
  int wave = t >> 6;
  int rowb = wave*16;                         // block-relative row base of this wave

  // A-frags for all k-steps (reused across 8 col-tiles)
  half8_t aA[NKS];
  #pragma unroll
  for(int ks = 0; ks < NKS; ks++)
    aA[ks] = *(const half8_t*)&sX[(rowb + l15)*KP + ks*32 + quad*8];

  f32x4 acc[8];
  #pragma unroll
  for(int ct = 0; ct < 8; ct++) acc[ct] = (f32x4){0.f,0.f,0.f,0.f};

  #pragma unroll
  for(int ct = 0; ct < 8; ct++){
    #pragma unroll
    for(int ks = 0; ks < NKS; ks++){
      half8_t bB = *(const half8_t*)&sW[(ct*16 + l15)*KP + ks*32 + quad*8];
      acc[ct] = __builtin_amdgcn_mfma_f32_16x16x32_f16(aA[ks], bB, acc[ct], 0, 0, 0);
    }
  }

  // epilogue: h16 store + per-head attention dots
  float ps0[4] = {0,0,0,0}, ps1[4] = {0,0,0,0};
  float pd0[4] = {0,0,0,0}, pd1[4] = {0,0,0,0};
  __half* h16h = (__half*)h16;
  #pragma unroll
  for(int ct = 0; ct < 8; ct++){
    int cabs = ct*16 + l15;
    float as = att_s[cabs];
    float ad = att_d[cabs];
    #pragma unroll
    for(int reg = 0; reg < 4; reg++){
      int row = row0 + rowb + quad*4 + reg;
      float v = acc[ct][reg];
      if(row < n) h16h[(size_t)row*128 + cabs] = __float2half(v);
      if(ct < 4){ ps0[reg] = fmaf(v, as, ps0[reg]); pd0[reg] = fmaf(v, ad, pd0[reg]); }
      else      { ps1[reg] = fmaf(v, as, ps1[reg]); pd1[reg] = fmaf(v, ad, pd1[reg]); }
    }
  }
  #pragma unroll
  for(int reg = 0; reg < 4; reg++){
    #pragma unroll
    for(int m = 1; m < 16; m <<= 1){
      ps0[reg] += __shfl_xor(ps0[reg], m);
      ps1[reg] += __shfl_xor(ps1[reg], m);
      pd0[reg] += __shfl_xor(pd0[reg], m);
      pd1[reg] += __shfl_xor(pd1[reg], m);
    }
    int row = row0 + rowb + quad*4 + reg;
    if(l15 == 0 && row < n){
      asrc[2*row]   = ps0[reg];
      asrc[2*row+1] = ps1[reg];
      adst[2*row]   = pd0[reg];
      adst[2*row+1] = pd1[reg];
    }
  }
}

// ---------------- softmax + aggregation: 4 nodes/wave, 16 lanes/node ----------------
template<int LAYER>
__global__ __launch_bounds__(256) void aggregate_kernel(
    const uint4* __restrict__ h16u4, const float2* __restrict__ asrc2, const float2* __restrict__ adst2,
    const int* __restrict__ rowptr, const int* __restrict__ esrc,
    const float* __restrict__ bias, const float* __restrict__ fcW, const float* __restrict__ fcb,
    float* __restrict__ out, int n)
{
  __shared__ float4 sE[16][CAP+1];
  int t = threadIdx.x;
  int p = t & 15;
  int slot = t >> 4;
  int node = blockIdx.x*16 + slot;
  bool valid = node < n;
  int nd = valid ? node : 0;
  int beg = rowptr[nd], end = rowptr[nd+1];
  if(!valid){ beg = 0; end = 0; }
  float2 adn = adst2[nd];

  float s0 = 0.f, s1 = 0.f;
  for(int i = beg + p; i < end; i += 16){
    int s = esrc[i];
    float2 av = asrc2[s];
    float e0 = av.x + adn.x; e0 = (e0 > 0.f) ? e0 : 0.2f*e0;
    float e1 = av.y + adn.y; e1 = (e1 > 0.f) ? e1 : 0.2f*e1;
    float w0 = __expf(e0), w1 = __expf(e1);
    s0 += w0; s1 += w1;
    int j = i - beg;
    if(j < CAP) sE[slot][j] = make_float4(w0, w1, __int_as_float(s), 0.f);
  }
  #pragma unroll
  for(int m = 1; m < 16; m <<= 1){ s0 += __shfl_xor(s0, m); s1 += __shfl_xor(s1, m); }
  float inv0 = 1.f/(s0 + 1e-16f), inv1 = 1.f/(s1 + 1e-16f);

  int deg = end - beg;
  int dcap = deg < CAP ? deg : CAP;
  for(int j = p; j < dcap; j += 16){
    float4 e = sE[slot][j];
    e.x *= inv0; e.y *= inv1;
    sE[slot][j] = e;
  }
  int maxd = dcap;
  maxd = max(maxd, __shfl_xor(maxd, 16));
  maxd = max(maxd, __shfl_xor(maxd, 32));

  bool head1 = p >= 8;
  float2 acc0 = make_float2(0.f,0.f), acc1 = acc0, acc2 = acc0, acc3 = acc0;

  #pragma unroll 4
  for(int j = 0; j < maxd; j++){
    float4 e = sE[slot][j];
    bool act = j < dcap;
    float alpha = act ? (head1 ? e.y : e.x) : 0.f;
    int s = act ? __float_as_int(e.z) : 0;
    uint4 hv = h16u4[(size_t)s*16 + p];
    const __half2 h0 = *(const __half2*)&hv.x;
    const __half2 h1 = *(const __half2*)&hv.y;
    const __half2 h2 = *(const __half2*)&hv.z;
    const __half2 h3 = *(const __half2*)&hv.w;
    acc0.x = fmaf(__half2float(h0.x), alpha, acc0.x);
    acc0.y = fmaf(__half2float(h0.y), alpha, acc0.y);
    acc1.x = fmaf(__half2float(h1.x), alpha, acc1.x);
    acc1.y = fmaf(__half2float(h1.y), alpha, acc1.y);
    acc2.x = fmaf(__half2float(h2.x), alpha, acc2.x);
    acc2.y = fmaf(__half2float(h2.y), alpha, acc2.y);
    acc3.x = fmaf(__half2float(h3.x), alpha, acc3.x);
    acc3.y = fmaf(__half2float(h3.y), alpha, acc3.y);
  }
  float inv_mine = head1 ? inv1 : inv0;
  float adh = head1 ? adn.y : adn.x;
  for(int i2 = beg + CAP; i2 < end; i2++){
    int s = esrc[i2];
    float2 av = asrc2[s];
    float e_ = (head1 ? av.y : av.x) + adh;
    e_ = (e_ > 0.f) ? e_ : 0.2f*e_;
    float alpha = __expf(e_) * inv_mine;
    uint4 hv = h16u4[(size_t)s*16 + p];
    const __half2 h0 = *(const __half2*)&hv.x;
    const __half2 h1 = *(const __half2*)&hv.y;
    const __half2 h2 = *(const __half2*)&hv.z;
    const __half2 h3 = *(const __half2*)&hv.w;
    acc0.x = fmaf(__half2float(h0.x), alpha, acc0.x);
    acc0.y = fmaf(__half2float(h0.y), alpha, acc0.y);
    acc1.x = fmaf(__half2float(h1.x), alpha, acc1.x);
    acc1.y = fmaf(__half2float(h1.y), alpha, acc1.y);
    acc2.x = fmaf(__half2float(h2.x), alpha, acc2.x);
    acc2.y = fmaf(__half2float(h2.y), alpha, acc2.y);
    acc3.x = fmaf(__half2float(h3.x), alpha, acc3.x);
    acc3.y = fmaf(__half2float(h3.y), alpha, acc3.y);
  }

  float o0 = acc0.x + __shfl_xor(acc0.x, 8);
  float o1 = acc0.y + __shfl_xor(acc0.y, 8);
  float o2 = acc1.x + __shfl_xor(acc1.x, 8);
  float o3 = acc1.y + __shfl_xor(acc1.y, 8);
  float o4 = acc2.x + __shfl_xor(acc2.x, 8);
  float o5 = acc2.y + __shfl_xor(acc2.y, 8);
  float o6 = acc3.x + __shfl_xor(acc3.x, 8);
  float o7 = acc3.y + __shfl_xor(acc3.y, 8);

  if(LAYER == 1){
    if(!head1 && valid){
      float4 b0 = ((const float4*)bias)[2*p];
      float4 b1 = ((const float4*)bias)[2*p+1];
      float4 r0 = make_float4(fmaxf(fmaf(0.5f,o0,b0.x),0.f), fmaxf(fmaf(0.5f,o1,b0.y),0.f),
                              fmaxf(fmaf(0.5f,o2,b0.z),0.f), fmaxf(fmaf(0.5f,o3,b0.w),0.f));
      float4 r1 = make_float4(fmaxf(fmaf(0.5f,o4,b1.x),0.f), fmaxf(fmaf(0.5f,o5,b1.y),0.f),
                              fmaxf(fmaf(0.5f,o6,b1.z),0.f), fmaxf(fmaf(0.5f,o7,b1.w),0.f));
      float4* orow = (float4*)(out + (size_t)node*64 + 8*p);
      orow[0] = r0; orow[1] = r1;
    }
  } else {
    float partial = 0.f;
    if(!head1){
      float4 b0 = ((const float4*)bias)[2*p];
      float4 b1 = ((const float4*)bias)[2*p+1];
      float4 w0 = ((const float4*)fcW)[2*p];
      float4 w1 = ((const float4*)fcW)[2*p+1];
      partial  = fmaxf(fmaf(0.5f,o0,b0.x),0.f)*w0.x + fmaxf(fmaf(0.5f,o1,b0.y),0.f)*w0.y
               + fmaxf(fmaf(0.5f,o2,b0.z),0.f)*w0.z + fmaxf(fmaf(0.5f,o3,b0.w),0.f)*w0.w
               + fmaxf(fmaf(0.5f,o4,b1.x),0.f)*w1.x + fmaxf(fmaf(0.5f,o5,b1.y),0.f)*w1.y
               + fmaxf(fmaf(0.5f,o6,b1.z),0.f)*w1.z + fmaxf(fmaf(0.5f,o7,b1.w),0.f)*w1.w;
    }
    partial += __shfl_xor(partial, 1);
    partial += __shfl_xor(partial, 2);
    partial += __shfl_xor(partial, 4);
    if(p == 0 && valid) out[node] = partial + fcb[0];
  }
}

// ---------------- launch ----------------
extern "C" void kernel_launch(void* const* d_in, const int* in_sizes, int n_in,
                              void* d_out, int out_size, void* d_ws, size_t ws_size,
                              hipStream_t stream)
{
  const float* x   = (const float*)d_in[0];
  const int*   ei  = (const int*)  d_in[1];
  const float* W1  = (const float*)d_in[2];
  const float* as1 = (const float*)d_in[3];
  const float* ad1 = (const float*)d_in[4];
  const float* b1  = (const float*)d_in[5];
  const float* W2  = (const float*)d_in[6];
  const float* as2 = (const float*)d_in[7];
  const float* ad2 = (const float*)d_in[8];
  const float* b2  = (const float*)d_in[9];
  const float* fcW = (const float*)d_in[10];
  const float* fcb = (const float*)d_in[11];
  float* out = (float*)d_out;

  char* ws = (char*)d_ws;
  size_t off = 0;
  auto alloc = [&](size_t bytes) -> void* {
    void* p = ws + off;
    off += (bytes + 255) & ~(size_t)255;
    return p;
  };
  int*          rowptr      = (int*)         alloc((NNODES+1)*sizeof(int));
  int*          bucketHist  = (int*)         alloc(NB*sizeof(int));
  int*          bucketBase  = (int*)         alloc((NB+1)*sizeof(int));
  int*          bucketCursor= (int*)         alloc(NB*sizeof(int));
  unsigned int* edgebuf     = (unsigned int*)alloc((size_t)EP*sizeof(unsigned int));
  int*          esrc        = (int*)         alloc((size_t)EP*sizeof(int));
  __half2*      h16         = (__half2*)     alloc((size_t)NNODES*64*sizeof(__half2));
  float*        asrc        = (float*)       alloc((size_t)NNODES*2*sizeof(float));
  float*        adst        = (float*)       alloc((size_t)NNODES*2*sizeof(float));
  float*        out1        = (float*)       alloc((size_t)NNODES*64*sizeof(float));
  __half*       Wt1         = (__half*)      alloc(16384*sizeof(__half));
  __half*       Wt2         = (__half*)      alloc(8192*sizeof(__half));

  const int nchunks = (EP + CHUNK - 1)/CHUNK;   // 104

  hipMemsetAsync(bucketHist, 0, NB*sizeof(int), stream);
  hipLaunchKernelGGL(transpose_w_kernel, dim3(96),      dim3(256), 0, stream, W1, W2, Wt1, Wt2);
  hipLaunchKernelGGL(bucket_hist_kernel, dim3(nchunks), dim3(256), 0, stream, ei, bucketHist);
  hipLaunchKernelGGL(bucket_scan_kernel, dim3(1),       dim3(256), 0, stream, bucketHist, bucketBase, bucketCursor, rowptr);
  hipLaunchKernelGGL(partition_kernel,   dim3(nchunks), dim3(256), 0, stream, ei, bucketCursor, edgebuf);
  hipLaunchKernelGGL(bucket_sort_kernel, dim3(NB),      dim3(256), 0, stream, edgebuf, bucketBase, rowptr, esrc);

  hipLaunchKernelGGL((gemm_att_kernel<128>), dim3((NNODES+63)/64), dim3(256), 0, stream,
                     x, Wt1, as1, ad1, h16, asrc, adst, NNODES);
  hipLaunchKernelGGL((aggregate_kernel<1>),  dim3((NNODES+15)/16), dim3(256), 0, stream,
                     (const uint4*)h16, (const float2*)asrc, (const float2*)adst, rowptr, esrc,
                     b1, (const float*)nullptr, (const float*)nullptr, out1, NNODES);
  hipLaunchKernelGGL((gemm_att_kernel<64>),  dim3((NNODES+63)/64), dim3(256), 0, stream,
                     out1, Wt2, as2, ad2, h16, asrc, adst, NNODES);
  hipLaunchKernelGGL((aggregate_kernel<2>),  dim3((NNODES+15)/16), dim3(256), 0, stream,
                     (const uint4*)h16, (const float2*)asrc, (const float2*)adst, rowptr, esrc,
                     b2, fcW, fcb, out, NNODES);
}

// Round 9
// 218.076 us; speedup vs baseline: 2.4300x; 1.0521x over previous
//
#include <hip/hip_runtime.h>
#include <hip/hip_fp16.h>

#define NNODES 50000
#define NEDGES 800000
#define EP (NEDGES + NNODES)   // 850000 edges incl. self-loops
#define CAP 64                 // per-node LDS edge cache in aggregate
#define NB 782                 // dst buckets of 64 nodes: ceil(50000/64)
#define CHUNK 8192             // edges per partition block
#define NPCH 104               // ceil(EP/CHUNK)

typedef _Float16 half8_t __attribute__((ext_vector_type(8)));
typedef float f32x4 __attribute__((ext_vector_type(4)));

// ---------------- fat kernel A: bucket hist (blocks 0..103) | W transpose (104..199) ----------------
__global__ __launch_bounds__(256) void hist_transpose_kernel(const int* __restrict__ ei, int* __restrict__ bucketHist,
                                                             const float* __restrict__ W1, const float* __restrict__ W2,
                                                             __half* __restrict__ Wt1, __half* __restrict__ Wt2){
  __shared__ int lh[NB];
  int t = threadIdx.x;
  if(blockIdx.x < NPCH){
    for(int i = t; i < NB; i += 256) lh[i] = 0;
    __syncthreads();
    int base = blockIdx.x*CHUNK;
    #pragma unroll
    for(int k = 0; k < CHUNK; k += 256){
      int e = base + k + t;
      if(e < EP){
        int d = (e < NEDGES) ? ei[NEDGES + e] : (e - NEDGES);
        atomicAdd(&lh[d >> 6], 1);
      }
    }
    __syncthreads();
    for(int i = t; i < NB; i += 256) if(lh[i]) atomicAdd(&bucketHist[i], lh[i]);
  } else {
    int g = (blockIdx.x - NPCH)*256 + t;
    if(g < 16384){
      int k = g >> 7, nn = g & 127;
      Wt1[nn*128 + k] = __float2half(W1[g]);
    } else if(g < 16384 + 8192){
      int i = g - 16384;
      int k = i >> 7, nn = i & 127;
      Wt2[nn*64 + k] = __float2half(W2[i]);
    }
  }
}

// ---------------- bucket scan: exclusive scan of NB counts (4 per thread) ----------------
__global__ __launch_bounds__(256) void bucket_scan_kernel(const int* __restrict__ bucketHist,
                                                          int* __restrict__ bucketBase,
                                                          int* __restrict__ bucketCursor,
                                                          int* __restrict__ rowptr){
  __shared__ int sm[256];
  int t = threadIdx.x, i0 = 4*t;
  int v0 = (i0   < NB) ? bucketHist[i0]   : 0;
  int v1 = (i0+1 < NB) ? bucketHist[i0+1] : 0;
  int v2 = (i0+2 < NB) ? bucketHist[i0+2] : 0;
  int v3 = (i0+3 < NB) ? bucketHist[i0+3] : 0;
  int s = v0+v1+v2+v3;
  sm[t] = s; __syncthreads();
  int acc = s;
  #pragma unroll
  for(int d = 1; d < 256; d <<= 1){
    int o = (t >= d) ? sm[t-d] : 0;
    __syncthreads();
    acc += o; sm[t] = acc;
    __syncthreads();
  }
  int e0 = acc - s, e1 = e0+v0, e2 = e1+v1, e3 = e2+v2;
  if(i0   < NB){ bucketBase[i0]   = e0; bucketCursor[i0]   = e0; }
  if(i0+1 < NB){ bucketBase[i0+1] = e1; bucketCursor[i0+1] = e1; }
  if(i0+2 < NB){ bucketBase[i0+2] = e2; bucketCursor[i0+2] = e2; }
  if(i0+3 < NB){ bucketBase[i0+3] = e3; bucketCursor[i0+3] = e3; }
  if(t == 0){ bucketBase[NB] = EP; rowptr[NNODES] = EP; }
}

// ---------------- partition body (uses caller smem, 46.3KB) ----------------
__device__ __forceinline__ void partition_body(char* smem, int blk, const int* __restrict__ ei,
                                               int* __restrict__ bucketCursor, unsigned int* __restrict__ edgebuf){
  unsigned int* stage = (unsigned int*)smem;           // 32768 B
  int* lh    = (int*)(smem + 32768);                   // 3128 B each
  int* lbase = (int*)(smem + 32768 + 3128);
  int* lcur  = (int*)(smem + 32768 + 2*3128);
  int* gbase = (int*)(smem + 32768 + 3*3128);
  int* sm    = (int*)(smem + 32768 + 4*3128);          // 1024 B
  int t = threadIdx.x;
  for(int i = t; i < NB; i += 256) lh[i] = 0;
  __syncthreads();
  int base = blk*CHUNK;
  unsigned int pk[CHUNK/256];
  #pragma unroll
  for(int k = 0; k < CHUNK/256; k++){
    int e = base + k*256 + t;
    unsigned int p = 0xffffffffu;            // valid pk < 0xC3500000
    if(e < EP){
      int s, d;
      if(e < NEDGES){ s = ei[e]; d = ei[NEDGES + e]; }
      else          { s = d = e - NEDGES; }
      p = ((unsigned int)d << 16) | (unsigned int)s;
      atomicAdd(&lh[d >> 6], 1);
    }
    pk[k] = p;
  }
  __syncthreads();
  int i0 = 4*t;
  int v0 = (i0   < NB) ? lh[i0]   : 0;
  int v1 = (i0+1 < NB) ? lh[i0+1] : 0;
  int v2 = (i0+2 < NB) ? lh[i0+2] : 0;
  int v3 = (i0+3 < NB) ? lh[i0+3] : 0;
  int s = v0+v1+v2+v3;
  sm[t] = s; __syncthreads();
  int acc = s;
  #pragma unroll
  for(int d = 1; d < 256; d <<= 1){
    int o = (t >= d) ? sm[t-d] : 0;
    __syncthreads();
    acc += o; sm[t] = acc;
    __syncthreads();
  }
  int e0 = acc - s, e1 = e0+v0, e2 = e1+v1, e3 = e2+v2;
  if(i0   < NB){ lbase[i0]  =e0; lcur[i0]  =e0; gbase[i0]  = v0?atomicAdd(&bucketCursor[i0],  v0):0; }
  if(i0+1 < NB){ lbase[i0+1]=e1; lcur[i0+1]=e1; gbase[i0+1]= v1?atomicAdd(&bucketCursor[i0+1],v1):0; }
  if(i0+2 < NB){ lbase[i0+2]=e2; lcur[i0+2]=e2; gbase[i0+2]= v2?atomicAdd(&bucketCursor[i0+2],v2):0; }
  if(i0+3 < NB){ lbase[i0+3]=e3; lcur[i0+3]=e3; gbase[i0+3]= v3?atomicAdd(&bucketCursor[i0+3],v3):0; }
  __syncthreads();
  #pragma unroll
  for(int k = 0; k < CHUNK/256; k++){
    unsigned int p = pk[k];
    if(p != 0xffffffffu){
      int bin = p >> 22;                     // d>>6
      int r = atomicAdd(&lcur[bin], 1);
      stage[r] = p;
    }
  }
  __syncthreads();
  int nvalid = EP - base; if(nvalid > CHUNK) nvalid = CHUNK;
  for(int j = t; j < nvalid; j += 256){
    unsigned int p = stage[j];
    int bin = p >> 22;
    edgebuf[gbase[bin] + (j - lbase[bin])] = p;
  }
}

// ---------------- bucket sort: one block per 64-node bucket ----------------
__global__ __launch_bounds__(256) void bucket_sort_kernel(const unsigned int* __restrict__ edgebuf,
                                                          const int* __restrict__ bucketBase,
                                                          int* __restrict__ rowptr,
                                                          int* __restrict__ esrc){
  __shared__ int lh[64], lcur[64], sb[64];
  int b = blockIdx.x, t = threadIdx.x;
  int lo = bucketBase[b], hi = bucketBase[b+1];
  if(t < 64) lh[t] = 0;
  __syncthreads();
  for(int i = lo + t; i < hi; i += 256)
    atomicAdd(&lh[(edgebuf[i] >> 16) & 63], 1);
  __syncthreads();
  int v = (t < 64) ? lh[t] : 0;
  if(t < 64) sb[t] = v;
  __syncthreads();
  int acc = v;
  #pragma unroll
  for(int d = 1; d < 64; d <<= 1){
    int o = (t >= d && t < 64) ? sb[t-d] : 0;
    __syncthreads();
    if(t < 64){ acc += o; sb[t] = acc; }
    __syncthreads();
  }
  if(t < 64){
    int excl = acc - v;
    lcur[t] = lo + excl;
    int node = b*64 + t;
    if(node < NNODES) rowptr[node] = lo + excl;
  }
  __syncthreads();
  for(int i = lo + t; i < hi; i += 256){
    unsigned int p = edgebuf[i];
    int pos = atomicAdd(&lcur[(p >> 16) & 63], 1);
    esrc[pos] = (int)(p & 0xffffu);
  }
}

// ---------------- MFMA GEMM body (round-8 verified) ----------------
template<int K>
__device__ __forceinline__ void gemm_body(__half* sX, __half* sW, int row0,
    const float* __restrict__ in, const __half* __restrict__ Wt,
    const float* __restrict__ att_s, const float* __restrict__ att_d,
    __half2* __restrict__ h16, float* __restrict__ asrc, float* __restrict__ adst, int n)
{
  constexpr int KP = K + 8;
  constexpr int NKS = K/32;
  int t = threadIdx.x;

  {
    const float4* in4 = (const float4*)in;
    const int nf4 = 64*K/4;
    const int maxi = n*(K/4) - 1;
    for(int i = t; i < nf4; i += 256){
      int r = i/(K/4), j = i%(K/4);
      int gi = row0*(K/4) + i;
      if(gi > maxi) gi = maxi;
      float4 v = in4[gi];
      __half2 p0 = __floats2half2_rn(v.x, v.y);
      __half2 p1 = __floats2half2_rn(v.z, v.w);
      uint2 pk;
      pk.x = *(unsigned int*)&p0;
      pk.y = *(unsigned int*)&p1;
      *(uint2*)&sX[r*KP + j*4] = pk;
    }
  }
  {
    const uint4* Wt4 = (const uint4*)Wt;
    const int nw = 128*K/8;
    for(int i = t; i < nw; i += 256){
      int r = i/(K/8), j = i%(K/8);
      *(uint4*)&sW[r*KP + j*8] = Wt4[i];
    }
  }
  __syncthreads();

  int lane = t & 63;
  int l15  = lane & 15;
  int quad = lane >> 4;
  int wave = t >> 6;
  int rowb = wave*16;

  half8_t aA[NKS];
  #pragma unroll
  for(int ks = 0; ks < NKS; ks++)
    aA[ks] = *(const half8_t*)&sX[(rowb + l15)*KP + ks*32 + quad*8];

  f32x4 acc[8];
  #pragma unroll
  for(int ct = 0; ct < 8; ct++) acc[ct] = (f32x4){0.f,0.f,0.f,0.f};

  #pragma unroll
  for(int ct = 0; ct < 8; ct++){
    #pragma unroll
    for(int ks = 0; ks < NKS; ks++){
      half8_t bB = *(const half8_t*)&sW[(ct*16 + l15)*KP + ks*32 + quad*8];
      acc[ct] = __builtin_amdgcn_mfma_f32_16x16x32_f16(aA[ks], bB, acc[ct], 0, 0, 0);
    }
  }

  float ps0[4] = {0,0,0,0}, ps1[4] = {0,0,0,0};
  float pd0[4] = {0,0,0,0}, pd1[4] = {0,0,0,0};
  __half* h16h = (__half*)h16;
  #pragma unroll
  for(int ct = 0; ct < 8; ct++){
    int cabs = ct*16 + l15;
    float as = att_s[cabs];
    float ad = att_d[cabs];
    #pragma unroll
    for(int reg = 0; reg < 4; reg++){
      int row = row0 + rowb + quad*4 + reg;
      float v = acc[ct][reg];
      if(row < n) h16h[(size_t)row*128 + cabs] = __float2half(v);
      if(ct < 4){ ps0[reg] = fmaf(v, as, ps0[reg]); pd0[reg] = fmaf(v, ad, pd0[reg]); }
      else      { ps1[reg] = fmaf(v, as, ps1[reg]); pd1[reg] = fmaf(v, ad, pd1[reg]); }
    }
  }
  #pragma unroll
  for(int reg = 0; reg < 4; reg++){
    #pragma unroll
    for(int m = 1; m < 16; m <<= 1){
      ps0[reg] += __shfl_xor(ps0[reg], m);
      ps1[reg] += __shfl_xor(ps1[reg], m);
      pd0[reg] += __shfl_xor(pd0[reg], m);
      pd1[reg] += __shfl_xor(pd1[reg], m);
    }
    int row = row0 + rowb + quad*4 + reg;
    if(l15 == 0 && row < n){
      asrc[2*row]   = ps0[reg];
      asrc[2*row+1] = ps1[reg];
      adst[2*row]   = pd0[reg];
      adst[2*row+1] = pd1[reg];
    }
  }
}

// fat kernel C: partition (blocks 0..103) | gemm1 K=128 (blocks 104..885)
__global__ __launch_bounds__(256, 3) void partition_gemm1_kernel(
    const int* __restrict__ ei, int* __restrict__ bucketCursor, unsigned int* __restrict__ edgebuf,
    const float* __restrict__ x, const __half* __restrict__ Wt1,
    const float* __restrict__ as1, const float* __restrict__ ad1,
    __half2* __restrict__ h16, float* __restrict__ asrc, float* __restrict__ adst)
{
  __shared__ __align__(16) char smem[52224];   // max(partition 46.3KB, gemm 52.2KB)
  if(blockIdx.x < NPCH){
    partition_body(smem, blockIdx.x, ei, bucketCursor, edgebuf);
  } else {
    gemm_body<128>((__half*)smem, (__half*)(smem + 17408), (blockIdx.x - NPCH)*64,
                   x, Wt1, as1, ad1, h16, asrc, adst, NNODES);
  }
}

// standalone gemm2 (K=64)
template<int K>
__global__ __launch_bounds__(256, 3) void gemm_att_kernel(
    const float* __restrict__ in, const __half* __restrict__ Wt,
    const float* __restrict__ att_s, const float* __restrict__ att_d,
    __half2* __restrict__ h16, float* __restrict__ asrc, float* __restrict__ adst, int n)
{
  constexpr int KP = K + 8;
  __shared__ __align__(16) __half sX[64*KP];
  __shared__ __align__(16) __half sW[128*KP];
  gemm_body<K>(sX, sW, blockIdx.x*64, in, Wt, att_s, att_d, h16, asrc, adst, n);
}

// ---------------- softmax + aggregation: 4 nodes/wave, 16 lanes/node ----------------
template<int LAYER>
__global__ __launch_bounds__(256) void aggregate_kernel(
    const uint4* __restrict__ h16u4, const float2* __restrict__ asrc2, const float2* __restrict__ adst2,
    const int* __restrict__ rowptr, const int* __restrict__ esrc,
    const float* __restrict__ bias, const float* __restrict__ fcW, const float* __restrict__ fcb,
    float* __restrict__ out, int n)
{
  __shared__ float4 sE[16][CAP+1];
  int t = threadIdx.x;
  int p = t & 15;
  int slot = t >> 4;
  int node = blockIdx.x*16 + slot;
  bool valid = node < n;
  int nd = valid ? node : 0;
  int beg = rowptr[nd], end = rowptr[nd+1];
  if(!valid){ beg = 0; end = 0; }
  float2 adn = adst2[nd];

  float s0 = 0.f, s1 = 0.f;
  for(int i = beg + p; i < end; i += 16){
    int s = esrc[i];
    float2 av = asrc2[s];
    float e0 = av.x + adn.x; e0 = (e0 > 0.f) ? e0 : 0.2f*e0;
    float e1 = av.y + adn.y; e1 = (e1 > 0.f) ? e1 : 0.2f*e1;
    float w0 = __expf(e0), w1 = __expf(e1);
    s0 += w0; s1 += w1;
    int j = i - beg;
    if(j < CAP) sE[slot][j] = make_float4(w0, w1, __int_as_float(s), 0.f);
  }
  #pragma unroll
  for(int m = 1; m < 16; m <<= 1){ s0 += __shfl_xor(s0, m); s1 += __shfl_xor(s1, m); }
  float inv0 = 1.f/(s0 + 1e-16f), inv1 = 1.f/(s1 + 1e-16f);

  int deg = end - beg;
  int dcap = deg < CAP ? deg : CAP;
  for(int j = p; j < dcap; j += 16){
    float4 e = sE[slot][j];
    e.x *= inv0; e.y *= inv1;
    sE[slot][j] = e;
  }
  int maxd = dcap;
  maxd = max(maxd, __shfl_xor(maxd, 16));
  maxd = max(maxd, __shfl_xor(maxd, 32));

  bool head1 = p >= 8;
  float2 acc0 = make_float2(0.f,0.f), acc1 = acc0, acc2 = acc0, acc3 = acc0;

  #pragma unroll 8
  for(int j = 0; j < maxd; j++){
    float4 e = sE[slot][j];
    bool act = j < dcap;
    float alpha = act ? (head1 ? e.y : e.x) : 0.f;
    int s = act ? __float_as_int(e.z) : 0;
    uint4 hv = h16u4[(size_t)s*16 + p];
    const __half2 h0 = *(const __half2*)&hv.x;
    const __half2 h1 = *(const __half2*)&hv.y;
    const __half2 h2 = *(const __half2*)&hv.z;
    const __half2 h3 = *(const __half2*)&hv.w;
    acc0.x = fmaf(__half2float(h0.x), alpha, acc0.x);
    acc0.y = fmaf(__half2float(h0.y), alpha, acc0.y);
    acc1.x = fmaf(__half2float(h1.x), alpha, acc1.x);
    acc1.y = fmaf(__half2float(h1.y), alpha, acc1.y);
    acc2.x = fmaf(__half2float(h2.x), alpha, acc2.x);
    acc2.y = fmaf(__half2float(h2.y), alpha, acc2.y);
    acc3.x = fmaf(__half2float(h3.x), alpha, acc3.x);
    acc3.y = fmaf(__half2float(h3.y), alpha, acc3.y);
  }
  float inv_mine = head1 ? inv1 : inv0;
  float adh = head1 ? adn.y : adn.x;
  for(int i2 = beg + CAP; i2 < end; i2++){
    int s = esrc[i2];
    float2 av = asrc2[s];
    float e_ = (head1 ? av.y : av.x) + adh;
    e_ = (e_ > 0.f) ? e_ : 0.2f*e_;
    float alpha = __expf(e_) * inv_mine;
    uint4 hv = h16u4[(size_t)s*16 + p];
    const __half2 h0 = *(const __half2*)&hv.x;
    const __half2 h1 = *(const __half2*)&hv.y;
    const __half2 h2 = *(const __half2*)&hv.z;
    const __half2 h3 = *(const __half2*)&hv.w;
    acc0.x = fmaf(__half2float(h0.x), alpha, acc0.x);
    acc0.y = fmaf(__half2float(h0.y), alpha, acc0.y);
    acc1.x = fmaf(__half2float(h1.x), alpha, acc1.x);
    acc1.y = fmaf(__half2float(h1.y), alpha, acc1.y);
    acc2.x = fmaf(__half2float(h2.x), alpha, acc2.x);
    acc2.y = fmaf(__half2float(h2.y), alpha, acc2.y);
    acc3.x = fmaf(__half2float(h3.x), alpha, acc3.x);
    acc3.y = fmaf(__half2float(h3.y), alpha, acc3.y);
  }

  float o0 = acc0.x + __shfl_xor(acc0.x, 8);
  float o1 = acc0.y + __shfl_xor(acc0.y, 8);
  float o2 = acc1.x + __shfl_xor(acc1.x, 8);
  float o3 = acc1.y + __shfl_xor(acc1.y, 8);
  float o4 = acc2.x + __shfl_xor(acc2.x, 8);
  float o5 = acc2.y + __shfl_xor(acc2.y, 8);
  float o6 = acc3.x + __shfl_xor(acc3.x, 8);
  float o7 = acc3.y + __shfl_xor(acc3.y, 8);

  if(LAYER == 1){
    if(!head1 && valid){
      float4 b0 = ((const float4*)bias)[2*p];
      float4 b1 = ((const float4*)bias)[2*p+1];
      float4 r0 = make_float4(fmaxf(fmaf(0.5f,o0,b0.x),0.f), fmaxf(fmaf(0.5f,o1,b0.y),0.f),
                              fmaxf(fmaf(0.5f,o2,b0.z),0.f), fmaxf(fmaf(0.5f,o3,b0.w),0.f));
      float4 r1 = make_float4(fmaxf(fmaf(0.5f,o4,b1.x),0.f), fmaxf(fmaf(0.5f,o5,b1.y),0.f),
                              fmaxf(fmaf(0.5f,o6,b1.z),0.f), fmaxf(fmaf(0.5f,o7,b1.w),0.f));
      float4* orow = (float4*)(out + (size_t)node*64 + 8*p);
      orow[0] = r0; orow[1] = r1;
    }
  } else {
    float partial = 0.f;
    if(!head1){
      float4 b0 = ((const float4*)bias)[2*p];
      float4 b1 = ((const float4*)bias)[2*p+1];
      float4 w0 = ((const float4*)fcW)[2*p];
      float4 w1 = ((const float4*)fcW)[2*p+1];
      partial  = fmaxf(fmaf(0.5f,o0,b0.x),0.f)*w0.x + fmaxf(fmaf(0.5f,o1,b0.y),0.f)*w0.y
               + fmaxf(fmaf(0.5f,o2,b0.z),0.f)*w0.z + fmaxf(fmaf(0.5f,o3,b0.w),0.f)*w0.w
               + fmaxf(fmaf(0.5f,o4,b1.x),0.f)*w1.x + fmaxf(fmaf(0.5f,o5,b1.y),0.f)*w1.y
               + fmaxf(fmaf(0.5f,o6,b1.z),0.f)*w1.z + fmaxf(fmaf(0.5f,o7,b1.w),0.f)*w1.w;
    }
    partial += __shfl_xor(partial, 1);
    partial += __shfl_xor(partial, 2);
    partial += __shfl_xor(partial, 4);
    if(p == 0 && valid) out[node] = partial + fcb[0];
  }
}

// ---------------- launch ----------------
extern "C" void kernel_launch(void* const* d_in, const int* in_sizes, int n_in,
                              void* d_out, int out_size, void* d_ws, size_t ws_size,
                              hipStream_t stream)
{
  const float* x   = (const float*)d_in[0];
  const int*   ei  = (const int*)  d_in[1];
  const float* W1  = (const float*)d_in[2];
  const float* as1 = (const float*)d_in[3];
  const float* ad1 = (const float*)d_in[4];
  const float* b1  = (const float*)d_in[5];
  const float* W2  = (const float*)d_in[6];
  const float* as2 = (const float*)d_in[7];
  const float* ad2 = (const float*)d_in[8];
  const float* b2  = (const float*)d_in[9];
  const float* fcW = (const float*)d_in[10];
  const float* fcb = (const float*)d_in[11];
  float* out = (float*)d_out;

  char* ws = (char*)d_ws;
  size_t off = 0;
  auto alloc = [&](size_t bytes) -> void* {
    void* p = ws + off;
    off += (bytes + 255) & ~(size_t)255;
    return p;
  };
  int*          rowptr      = (int*)         alloc((NNODES+1)*sizeof(int));
  int*          bucketHist  = (int*)         alloc(NB*sizeof(int));
  int*          bucketBase  = (int*)         alloc((NB+1)*sizeof(int));
  int*          bucketCursor= (int*)         alloc(NB*sizeof(int));
  unsigned int* edgebuf     = (unsigned int*)alloc((size_t)EP*sizeof(unsigned int));
  int*          esrc        = (int*)         alloc((size_t)EP*sizeof(int));
  __half2*      h16         = (__half2*)     alloc((size_t)NNODES*64*sizeof(__half2));
  float*        asrc        = (float*)       alloc((size_t)NNODES*2*sizeof(float));
  float*        adst        = (float*)       alloc((size_t)NNODES*2*sizeof(float));
  float*        out1        = (float*)       alloc((size_t)NNODES*64*sizeof(float));
  __half*       Wt1         = (__half*)      alloc(16384*sizeof(__half));
  __half*       Wt2         = (__half*)      alloc(8192*sizeof(__half));

  hipMemsetAsync(bucketHist, 0, NB*sizeof(int), stream);
  hipLaunchKernelGGL(hist_transpose_kernel, dim3(NPCH + 96), dim3(256), 0, stream,
                     ei, bucketHist, W1, W2, Wt1, Wt2);
  hipLaunchKernelGGL(bucket_scan_kernel,    dim3(1),         dim3(256), 0, stream,
                     bucketHist, bucketBase, bucketCursor, rowptr);
  hipLaunchKernelGGL(partition_gemm1_kernel, dim3(NPCH + (NNODES+63)/64), dim3(256), 0, stream,
                     ei, bucketCursor, edgebuf, x, Wt1, as1, ad1, h16, asrc, adst);
  hipLaunchKernelGGL(bucket_sort_kernel,    dim3(NB),        dim3(256), 0, stream,
                     edgebuf, bucketBase, rowptr, esrc);

  hipLaunchKernelGGL((aggregate_kernel<1>), dim3((NNODES+15)/16), dim3(256), 0, stream,
                     (const uint4*)h16, (const float2*)asrc, (const float2*)adst, rowptr, esrc,
                     b1, (const float*)nullptr, (const float*)nullptr, out1, NNODES);
  hipLaunchKernelGGL((gemm_att_kernel<64>), dim3((NNODES+63)/64), dim3(256), 0, stream,
                     out1, Wt2, as2, ad2, h16, asrc, adst, NNODES);
  hipLaunchKernelGGL((aggregate_kernel<2>), dim3((NNODES+15)/16), dim3(256), 0, stream,
                     (const uint4*)h16, (const float2*)asrc, (const float2*)adst, rowptr, esrc,
                     b2, fcW, fcb, out, NNODES);
}

// Round 10
// 191.273 us; speedup vs baseline: 2.7705x; 1.1401x over previous
//
#include <hip/hip_runtime.h>
#include <hip/hip_fp16.h>

#define NNODES 50000
#define NEDGES 800000
#define EP (NEDGES + NNODES)   // 850000 edges incl. self-loops
#define CAP 64                 // per-node LDS edge cache in aggregate
#define NB 782                 // dst buckets of 64 nodes: ceil(50000/64)
#define SEGCAP 2048            // slots per bucket segment (exp 1088, sigma 33 -> +29 sigma)
#define CHUNK 8192             // edges per partition block
#define NPCH 104               // ceil(EP/CHUNK)

typedef _Float16 half8_t __attribute__((ext_vector_type(8)));
typedef float f32x4 __attribute__((ext_vector_type(4)));

// ---------------- setup: per-bucket cursor init + W transpose->fp16 ----------------
__global__ __launch_bounds__(256) void setup_kernel(int* __restrict__ cursorB,
                                                    const float* __restrict__ W1, const float* __restrict__ W2,
                                                    __half* __restrict__ Wt1, __half* __restrict__ Wt2){
  int g = blockIdx.x*256 + threadIdx.x;
  if(g < NB) cursorB[g] = g*SEGCAP;
  int h = g - 1024;
  if(h >= 0){
    if(h < 16384){
      int k = h >> 7, nn = h & 127;
      Wt1[nn*128 + k] = __float2half(W1[h]);
    } else if(h < 24576){
      int i = h - 16384;
      int k = i >> 7, nn = i & 127;
      Wt2[nn*64 + k] = __float2half(W2[i]);
    }
  }
}

// ---------------- partition body (caller smem, 46.3KB) ----------------
// packs pk=(d<<16)|s into segmented edgebuf[bucket*SEGCAP + cursor++] via LDS staging
__device__ __forceinline__ void partition_body(char* smem, int blk, const int* __restrict__ ei,
                                               int* __restrict__ cursorB, unsigned int* __restrict__ edgebuf){
  unsigned int* stage = (unsigned int*)smem;           // 32768 B
  int* lh    = (int*)(smem + 32768);                   // 3128 B each
  int* lbase = (int*)(smem + 32768 + 3128);
  int* lcur  = (int*)(smem + 32768 + 2*3128);
  int* gbase = (int*)(smem + 32768 + 3*3128);
  int* sm    = (int*)(smem + 32768 + 4*3128);          // 1024 B
  int t = threadIdx.x;
  for(int i = t; i < NB; i += 256) lh[i] = 0;
  __syncthreads();
  int base = blk*CHUNK;
  unsigned int pk[CHUNK/256];
  #pragma unroll
  for(int k = 0; k < CHUNK/256; k++){
    int e = base + k*256 + t;
    unsigned int p = 0xffffffffu;
    if(e < EP){
      int s, d;
      if(e < NEDGES){ s = ei[e]; d = ei[NEDGES + e]; }
      else          { s = d = e - NEDGES; }
      p = ((unsigned int)d << 16) | (unsigned int)s;
      atomicAdd(&lh[d >> 6], 1);
    }
    pk[k] = p;
  }
  __syncthreads();
  int i0 = 4*t;
  int v0 = (i0   < NB) ? lh[i0]   : 0;
  int v1 = (i0+1 < NB) ? lh[i0+1] : 0;
  int v2 = (i0+2 < NB) ? lh[i0+2] : 0;
  int v3 = (i0+3 < NB) ? lh[i0+3] : 0;
  int s = v0+v1+v2+v3;
  sm[t] = s; __syncthreads();
  int acc = s;
  #pragma unroll
  for(int d = 1; d < 256; d <<= 1){
    int o = (t >= d) ? sm[t-d] : 0;
    __syncthreads();
    acc += o; sm[t] = acc;
    __syncthreads();
  }
  int e0 = acc - s, e1 = e0+v0, e2 = e1+v1, e3 = e2+v2;
  if(i0   < NB){ lbase[i0]  =e0; lcur[i0]  =e0; gbase[i0]  = v0?atomicAdd(&cursorB[i0],  v0):0; }
  if(i0+1 < NB){ lbase[i0+1]=e1; lcur[i0+1]=e1; gbase[i0+1]= v1?atomicAdd(&cursorB[i0+1],v1):0; }
  if(i0+2 < NB){ lbase[i0+2]=e2; lcur[i0+2]=e2; gbase[i0+2]= v2?atomicAdd(&cursorB[i0+2],v2):0; }
  if(i0+3 < NB){ lbase[i0+3]=e3; lcur[i0+3]=e3; gbase[i0+3]= v3?atomicAdd(&cursorB[i0+3],v3):0; }
  __syncthreads();
  #pragma unroll
  for(int k = 0; k < CHUNK/256; k++){
    unsigned int p = pk[k];
    if(p != 0xffffffffu){
      int bin = p >> 22;
      int r = atomicAdd(&lcur[bin], 1);
      stage[r] = p;
    }
  }
  __syncthreads();
  int nvalid = EP - base; if(nvalid > CHUNK) nvalid = CHUNK;
  for(int j = t; j < nvalid; j += 256){
    unsigned int p = stage[j];
    int bin = p >> 22;
    edgebuf[gbase[bin] + (j - lbase[bin])] = p;
  }
}

// ---------------- bucket sort: one block per 64-node bucket -> packed (beg<<9|deg) + esrc ----------------
__global__ __launch_bounds__(256) void bucket_sort_kernel(const unsigned int* __restrict__ edgebuf,
                                                          const int* __restrict__ cursorB,
                                                          int* __restrict__ pb,
                                                          int* __restrict__ esrc){
  __shared__ int lh[64], lcur[64], sb[64];
  int b = blockIdx.x, t = threadIdx.x;
  int lo = b*SEGCAP, hi = cursorB[b];
  if(t < 64) lh[t] = 0;
  __syncthreads();
  for(int i = lo + t; i < hi; i += 256)
    atomicAdd(&lh[(edgebuf[i] >> 16) & 63], 1);
  __syncthreads();
  int v = (t < 64) ? lh[t] : 0;
  if(t < 64) sb[t] = v;
  __syncthreads();
  int acc = v;
  #pragma unroll
  for(int d = 1; d < 64; d <<= 1){
    int o = (t >= d && t < 64) ? sb[t-d] : 0;
    __syncthreads();
    if(t < 64){ acc += o; sb[t] = acc; }
    __syncthreads();
  }
  if(t < 64){
    int excl = acc - v;
    int begAbs = lo + excl;
    lcur[t] = begAbs;
    int node = b*64 + t;
    int deg = v > 511 ? 511 : v;
    if(node < NNODES) pb[node] = (begAbs << 9) | deg;
  }
  __syncthreads();
  for(int i = lo + t; i < hi; i += 256){
    unsigned int p = edgebuf[i];
    int pos = atomicAdd(&lcur[(p >> 16) & 63], 1);
    esrc[pos] = (int)(p & 0xffffu);
  }
}

// ---------------- MFMA GEMM body (round-8 verified) ----------------
template<int K>
__device__ __forceinline__ void gemm_body(__half* sX, __half* sW, int row0,
    const float* __restrict__ in, const __half* __restrict__ Wt,
    const float* __restrict__ att_s, const float* __restrict__ att_d,
    __half2* __restrict__ h16, float* __restrict__ asrc, float* __restrict__ adst, int n)
{
  constexpr int KP = K + 8;
  constexpr int NKS = K/32;
  int t = threadIdx.x;

  {
    const float4* in4 = (const float4*)in;
    const int nf4 = 64*K/4;
    const int maxi = n*(K/4) - 1;
    for(int i = t; i < nf4; i += 256){
      int r = i/(K/4), j = i%(K/4);
      int gi = row0*(K/4) + i;
      if(gi > maxi) gi = maxi;
      float4 v = in4[gi];
      __half2 p0 = __floats2half2_rn(v.x, v.y);
      __half2 p1 = __floats2half2_rn(v.z, v.w);
      uint2 pk;
      pk.x = *(unsigned int*)&p0;
      pk.y = *(unsigned int*)&p1;
      *(uint2*)&sX[r*KP + j*4] = pk;
    }
  }
  {
    const uint4* Wt4 = (const uint4*)Wt;
    const int nw = 128*K/8;
    for(int i = t; i < nw; i += 256){
      int r = i/(K/8), j = i%(K/8);
      *(uint4*)&sW[r*KP + j*8] = Wt4[i];
    }
  }
  __syncthreads();

  int lane = t & 63;
  int l15  = lane & 15;
  int quad = lane >> 4;
  int wave = t >> 6;
  int rowb = wave*16;

  half8_t aA[NKS];
  #pragma unroll
  for(int ks = 0; ks < NKS; ks++)
    aA[ks] = *(const half8_t*)&sX[(rowb + l15)*KP + ks*32 + quad*8];

  f32x4 acc[8];
  #pragma unroll
  for(int ct = 0; ct < 8; ct++) acc[ct] = (f32x4){0.f,0.f,0.f,0.f};

  #pragma unroll
  for(int ct = 0; ct < 8; ct++){
    #pragma unroll
    for(int ks = 0; ks < NKS; ks++){
      half8_t bB = *(const half8_t*)&sW[(ct*16 + l15)*KP + ks*32 + quad*8];
      acc[ct] = __builtin_amdgcn_mfma_f32_16x16x32_f16(aA[ks], bB, acc[ct], 0, 0, 0);
    }
  }

  float ps0[4] = {0,0,0,0}, ps1[4] = {0,0,0,0};
  float pd0[4] = {0,0,0,0}, pd1[4] = {0,0,0,0};
  __half* h16h = (__half*)h16;
  #pragma unroll
  for(int ct = 0; ct < 8; ct++){
    int cabs = ct*16 + l15;
    float as = att_s[cabs];
    float ad = att_d[cabs];
    #pragma unroll
    for(int reg = 0; reg < 4; reg++){
      int row = row0 + rowb + quad*4 + reg;
      float v = acc[ct][reg];
      if(row < n) h16h[(size_t)row*128 + cabs] = __float2half(v);
      if(ct < 4){ ps0[reg] = fmaf(v, as, ps0[reg]); pd0[reg] = fmaf(v, ad, pd0[reg]); }
      else      { ps1[reg] = fmaf(v, as, ps1[reg]); pd1[reg] = fmaf(v, ad, pd1[reg]); }
    }
  }
  #pragma unroll
  for(int reg = 0; reg < 4; reg++){
    #pragma unroll
    for(int m = 1; m < 16; m <<= 1){
      ps0[reg] += __shfl_xor(ps0[reg], m);
      ps1[reg] += __shfl_xor(ps1[reg], m);
      pd0[reg] += __shfl_xor(pd0[reg], m);
      pd1[reg] += __shfl_xor(pd1[reg], m);
    }
    int row = row0 + rowb + quad*4 + reg;
    if(l15 == 0 && row < n){
      asrc[2*row]   = ps0[reg];
      asrc[2*row+1] = ps1[reg];
      adst[2*row]   = pd0[reg];
      adst[2*row+1] = pd1[reg];
    }
  }
}

// fat kernel: partition (blocks 0..103) | gemm1 K=128 (blocks 104..885)
__global__ __launch_bounds__(256, 3) void partition_gemm1_kernel(
    const int* __restrict__ ei, int* __restrict__ cursorB, unsigned int* __restrict__ edgebuf,
    const float* __restrict__ x, const __half* __restrict__ Wt1,
    const float* __restrict__ as1, const float* __restrict__ ad1,
    __half2* __restrict__ h16, float* __restrict__ asrc, float* __restrict__ adst)
{
  __shared__ __align__(16) char smem[52224];
  if(blockIdx.x < NPCH){
    partition_body(smem, blockIdx.x, ei, cursorB, edgebuf);
  } else {
    gemm_body<128>((__half*)smem, (__half*)(smem + 17408), (blockIdx.x - NPCH)*64,
                   x, Wt1, as1, ad1, h16, asrc, adst, NNODES);
  }
}

// ---------------- softmax + aggregation (16 lanes/node); LAYER 1 fuses gemm2 on wave 0 ----------------
// NNODES = 3125*16 exactly -> every slot valid.
template<int LAYER>
__global__ __launch_bounds__(256) void aggregate_kernel(
    const uint4* __restrict__ h16u4, const float2* __restrict__ asrc2, const float2* __restrict__ adst2,
    const int* __restrict__ pb, const int* __restrict__ esrc,
    const float* __restrict__ bias,
    const __half* __restrict__ Wt2, const float* __restrict__ as2, const float* __restrict__ ad2,
    __half2* __restrict__ h16out, float* __restrict__ asrcOut, float* __restrict__ adstOut,
    const float* __restrict__ fcW, const float* __restrict__ fcb,
    float* __restrict__ out)
{
  __shared__ __align__(16) char um[(LAYER == 1) ? 20736 : 16640];
  float4* sE = (float4*)um;                       // [16][CAP+1]
  int t = threadIdx.x;
  int p = t & 15;
  int slot = t >> 4;
  int node = blockIdx.x*16 + slot;
  int pbv = pb[node];
  int beg = pbv >> 9, deg9 = pbv & 511;
  int end = beg + deg9;
  float2 adn = adst2[node];

  float s0 = 0.f, s1 = 0.f;
  for(int i = beg + p; i < end; i += 16){
    int s = esrc[i];
    float2 av = asrc2[s];
    float e0 = av.x + adn.x; e0 = (e0 > 0.f) ? e0 : 0.2f*e0;
    float e1 = av.y + adn.y; e1 = (e1 > 0.f) ? e1 : 0.2f*e1;
    float w0 = __expf(e0), w1 = __expf(e1);
    s0 += w0; s1 += w1;
    int j = i - beg;
    if(j < CAP) sE[slot*(CAP+1) + j] = make_float4(w0, w1, __int_as_float(s), 0.f);
  }
  #pragma unroll
  for(int m = 1; m < 16; m <<= 1){ s0 += __shfl_xor(s0, m); s1 += __shfl_xor(s1, m); }
  float inv0 = 1.f/(s0 + 1e-16f), inv1 = 1.f/(s1 + 1e-16f);

  int dcap = deg9 < CAP ? deg9 : CAP;
  for(int j = p; j < dcap; j += 16){
    float4 e = sE[slot*(CAP+1) + j];
    e.x *= inv0; e.y *= inv1;
    sE[slot*(CAP+1) + j] = e;
  }
  int maxd = dcap;
  maxd = max(maxd, __shfl_xor(maxd, 16));
  maxd = max(maxd, __shfl_xor(maxd, 32));

  bool head1 = p >= 8;
  float2 acc0 = make_float2(0.f,0.f), acc1 = acc0, acc2 = acc0, acc3 = acc0;

  #pragma unroll 8
  for(int j = 0; j < maxd; j++){
    float4 e = sE[slot*(CAP+1) + j];
    bool act = j < dcap;
    float alpha = act ? (head1 ? e.y : e.x) : 0.f;
    int s = act ? __float_as_int(e.z) : 0;
    uint4 hv = h16u4[(size_t)s*16 + p];
    const __half2 h0 = *(const __half2*)&hv.x;
    const __half2 h1 = *(const __half2*)&hv.y;
    const __half2 h2 = *(const __half2*)&hv.z;
    const __half2 h3 = *(const __half2*)&hv.w;
    acc0.x = fmaf(__half2float(h0.x), alpha, acc0.x);
    acc0.y = fmaf(__half2float(h0.y), alpha, acc0.y);
    acc1.x = fmaf(__half2float(h1.x), alpha, acc1.x);
    acc1.y = fmaf(__half2float(h1.y), alpha, acc1.y);
    acc2.x = fmaf(__half2float(h2.x), alpha, acc2.x);
    acc2.y = fmaf(__half2float(h2.y), alpha, acc2.y);
    acc3.x = fmaf(__half2float(h3.x), alpha, acc3.x);
    acc3.y = fmaf(__half2float(h3.y), alpha, acc3.y);
  }
  float inv_mine = head1 ? inv1 : inv0;
  float adh = head1 ? adn.y : adn.x;
  for(int i2 = beg + CAP; i2 < end; i2++){
    int s = esrc[i2];
    float2 av = asrc2[s];
    float e_ = (head1 ? av.y : av.x) + adh;
    e_ = (e_ > 0.f) ? e_ : 0.2f*e_;
    float alpha = __expf(e_) * inv_mine;
    uint4 hv = h16u4[(size_t)s*16 + p];
    const __half2 h0 = *(const __half2*)&hv.x;
    const __half2 h1 = *(const __half2*)&hv.y;
    const __half2 h2 = *(const __half2*)&hv.z;
    const __half2 h3 = *(const __half2*)&hv.w;
    acc0.x = fmaf(__half2float(h0.x), alpha, acc0.x);
    acc0.y = fmaf(__half2float(h0.y), alpha, acc0.y);
    acc1.x = fmaf(__half2float(h1.x), alpha, acc1.x);
    acc1.y = fmaf(__half2float(h1.y), alpha, acc1.y);
    acc2.x = fmaf(__half2float(h2.x), alpha, acc2.x);
    acc2.y = fmaf(__half2float(h2.y), alpha, acc2.y);
    acc3.x = fmaf(__half2float(h3.x), alpha, acc3.x);
    acc3.y = fmaf(__half2float(h3.y), alpha, acc3.y);
  }

  float o0 = acc0.x + __shfl_xor(acc0.x, 8);
  float o1 = acc0.y + __shfl_xor(acc0.y, 8);
  float o2 = acc1.x + __shfl_xor(acc1.x, 8);
  float o3 = acc1.y + __shfl_xor(acc1.y, 8);
  float o4 = acc2.x + __shfl_xor(acc2.x, 8);
  float o5 = acc2.y + __shfl_xor(acc2.y, 8);
  float o6 = acc3.x + __shfl_xor(acc3.x, 8);
  float o7 = acc3.y + __shfl_xor(acc3.y, 8);

  if constexpr (LAYER == 1){
    // out1 row (relu(0.5*o + b)) -> fp16 into sA (offset 18432, does NOT overlap sE)
    __half* sA = (__half*)(um + 18432);            // [16][72]
    if(!head1){
      float4 b0 = ((const float4*)bias)[2*p];
      float4 b1 = ((const float4*)bias)[2*p+1];
      float v0 = fmaxf(fmaf(0.5f,o0,b0.x),0.f), v1 = fmaxf(fmaf(0.5f,o1,b0.y),0.f);
      float v2 = fmaxf(fmaf(0.5f,o2,b0.z),0.f), v3 = fmaxf(fmaf(0.5f,o3,b0.w),0.f);
      float v4 = fmaxf(fmaf(0.5f,o4,b1.x),0.f), v5 = fmaxf(fmaf(0.5f,o5,b1.y),0.f);
      float v6 = fmaxf(fmaf(0.5f,o6,b1.z),0.f), v7 = fmaxf(fmaf(0.5f,o7,b1.w),0.f);
      __half2 q0 = __floats2half2_rn(v0, v1);
      __half2 q1 = __floats2half2_rn(v2, v3);
      __half2 q2 = __floats2half2_rn(v4, v5);
      __half2 q3 = __floats2half2_rn(v6, v7);
      uint4 pk;
      pk.x = *(unsigned int*)&q0; pk.y = *(unsigned int*)&q1;
      pk.z = *(unsigned int*)&q2; pk.w = *(unsigned int*)&q3;
      *(uint4*)&sA[slot*72 + 8*p] = pk;
    }
    __syncthreads();                                // sE consumed, sA written
    // stage Wt2 [128][64] -> sW2 (reuses sE region, stride 72)
    __half* sW2 = (__half*)um;
    {
      const uint4* Wt4 = (const uint4*)Wt2;
      #pragma unroll
      for(int i = 0; i < 4; i++){
        int idx = t + i*256;                        // 1024 uint4
        int r = idx >> 3, j = idx & 7;
        *(uint4*)&sW2[r*72 + j*8] = Wt4[idx];
      }
    }
    __syncthreads();
    if(t < 64){                                     // wave 0: 16x128 gemm2, K=64
      int l15 = t & 15, quad = t >> 4;
      half8_t aA[2];
      #pragma unroll
      for(int ks = 0; ks < 2; ks++)
        aA[ks] = *(const half8_t*)&sA[l15*72 + ks*32 + quad*8];
      f32x4 acc[8];
      #pragma unroll
      for(int ct = 0; ct < 8; ct++) acc[ct] = (f32x4){0.f,0.f,0.f,0.f};
      #pragma unroll
      for(int ct = 0; ct < 8; ct++){
        #pragma unroll
        for(int ks = 0; ks < 2; ks++){
          half8_t bB = *(const half8_t*)&sW2[(ct*16 + l15)*72 + ks*32 + quad*8];
          acc[ct] = __builtin_amdgcn_mfma_f32_16x16x32_f16(aA[ks], bB, acc[ct], 0, 0, 0);
        }
      }
      int row0 = blockIdx.x*16;
      float ps0[4] = {0,0,0,0}, ps1[4] = {0,0,0,0};
      float pd0[4] = {0,0,0,0}, pd1[4] = {0,0,0,0};
      __half* hh = (__half*)h16out;
      #pragma unroll
      for(int ct = 0; ct < 8; ct++){
        int cabs = ct*16 + l15;
        float as = as2[cabs];
        float ad = ad2[cabs];
        #pragma unroll
        for(int reg = 0; reg < 4; reg++){
          int row = row0 + quad*4 + reg;
          float v = acc[ct][reg];
          hh[(size_t)row*128 + cabs] = __float2half(v);
          if(ct < 4){ ps0[reg] = fmaf(v, as, ps0[reg]); pd0[reg] = fmaf(v, ad, pd0[reg]); }
          else      { ps1[reg] = fmaf(v, as, ps1[reg]); pd1[reg] = fmaf(v, ad, pd1[reg]); }
        }
      }
      #pragma unroll
      for(int reg = 0; reg < 4; reg++){
        #pragma unroll
        for(int m = 1; m < 16; m <<= 1){
          ps0[reg] += __shfl_xor(ps0[reg], m);
          ps1[reg] += __shfl_xor(ps1[reg], m);
          pd0[reg] += __shfl_xor(pd0[reg], m);
          pd1[reg] += __shfl_xor(pd1[reg], m);
        }
        int row = row0 + quad*4 + reg;
        if(l15 == 0){
          asrcOut[2*row]   = ps0[reg];
          asrcOut[2*row+1] = ps1[reg];
          adstOut[2*row]   = pd0[reg];
          adstOut[2*row+1] = pd1[reg];
        }
      }
    }
  } else {
    float partial = 0.f;
    if(!head1){
      float4 b0 = ((const float4*)bias)[2*p];
      float4 b1 = ((const float4*)bias)[2*p+1];
      float4 w0 = ((const float4*)fcW)[2*p];
      float4 w1 = ((const float4*)fcW)[2*p+1];
      partial  = fmaxf(fmaf(0.5f,o0,b0.x),0.f)*w0.x + fmaxf(fmaf(0.5f,o1,b0.y),0.f)*w0.y
               + fmaxf(fmaf(0.5f,o2,b0.z),0.f)*w0.z + fmaxf(fmaf(0.5f,o3,b0.w),0.f)*w0.w
               + fmaxf(fmaf(0.5f,o4,b1.x),0.f)*w1.x + fmaxf(fmaf(0.5f,o5,b1.y),0.f)*w1.y
               + fmaxf(fmaf(0.5f,o6,b1.z),0.f)*w1.z + fmaxf(fmaf(0.5f,o7,b1.w),0.f)*w1.w;
    }
    partial += __shfl_xor(partial, 1);
    partial += __shfl_xor(partial, 2);
    partial += __shfl_xor(partial, 4);
    if(p == 0) out[node] = partial + fcb[0];
  }
}

// ---------------- launch ----------------
extern "C" void kernel_launch(void* const* d_in, const int* in_sizes, int n_in,
                              void* d_out, int out_size, void* d_ws, size_t ws_size,
                              hipStream_t stream)
{
  const float* x   = (const float*)d_in[0];
  const int*   ei  = (const int*)  d_in[1];
  const float* W1  = (const float*)d_in[2];
  const float* as1 = (const float*)d_in[3];
  const float* ad1 = (const float*)d_in[4];
  const float* b1  = (const float*)d_in[5];
  const float* W2  = (const float*)d_in[6];
  const float* as2 = (const float*)d_in[7];
  const float* ad2 = (const float*)d_in[8];
  const float* b2  = (const float*)d_in[9];
  const float* fcW = (const float*)d_in[10];
  const float* fcb = (const float*)d_in[11];
  float* out = (float*)d_out;

  char* ws = (char*)d_ws;
  size_t off = 0;
  auto alloc = [&](size_t bytes) -> void* {
    void* p = ws + off;
    off += (bytes + 255) & ~(size_t)255;
    return p;
  };
  int*          pb       = (int*)         alloc(NNODES*sizeof(int));
  int*          cursorB  = (int*)         alloc(NB*sizeof(int));
  unsigned int* edgebuf  = (unsigned int*)alloc((size_t)NB*SEGCAP*sizeof(unsigned int));
  int*          esrc     = (int*)         alloc((size_t)NB*SEGCAP*sizeof(int));
  __half2*      h16      = (__half2*)     alloc((size_t)NNODES*64*sizeof(__half2));
  __half2*      h16b     = (__half2*)     alloc((size_t)NNODES*64*sizeof(__half2));
  float*        asrc     = (float*)       alloc((size_t)NNODES*2*sizeof(float));
  float*        adst     = (float*)       alloc((size_t)NNODES*2*sizeof(float));
  float*        asrcB    = (float*)       alloc((size_t)NNODES*2*sizeof(float));
  float*        adstB    = (float*)       alloc((size_t)NNODES*2*sizeof(float));
  __half*       Wt1      = (__half*)      alloc(16384*sizeof(__half));
  __half*       Wt2      = (__half*)      alloc(8192*sizeof(__half));

  hipLaunchKernelGGL(setup_kernel, dim3(100), dim3(256), 0, stream, cursorB, W1, W2, Wt1, Wt2);
  hipLaunchKernelGGL(partition_gemm1_kernel, dim3(NPCH + (NNODES+63)/64), dim3(256), 0, stream,
                     ei, cursorB, edgebuf, x, Wt1, as1, ad1, h16, asrc, adst);
  hipLaunchKernelGGL(bucket_sort_kernel, dim3(NB), dim3(256), 0, stream,
                     edgebuf, cursorB, pb, esrc);
  hipLaunchKernelGGL((aggregate_kernel<1>), dim3(NNODES/16), dim3(256), 0, stream,
                     (const uint4*)h16, (const float2*)asrc, (const float2*)adst, pb, esrc,
                     b1, Wt2, as2, ad2, h16b, asrcB, adstB,
                     (const float*)nullptr, (const float*)nullptr, (float*)nullptr);
  hipLaunchKernelGGL((aggregate_kernel<2>), dim3(NNODES/16), dim3(256), 0, stream,
                     (const uint4*)h16b, (const float2*)asrcB, (const float2*)adstB, pb, esrc,
                     b2, (const __half*)nullptr, (const float*)nullptr, (const float*)nullptr,
                     (__half2*)nullptr, (float*)nullptr, (float*)nullptr,
                     fcW, fcb, out);
}